// Round 1
// baseline (644.142 us; speedup 1.0000x reference)
//
#include <hip/hip_runtime.h>
#include <math.h>

#define EMBED 512
#define HEADS 8
#define HDIM 64
#define SLEN 2048
#define BATCH 2
#define HALFW 128
#define INV_SCALE 0.044194173824159216f  // 1/sqrt(512)

// ---------------------------------------------------------------------------
// Kernel 1: vsum[b][e] = sum over valid j of v[b][j][e]; nvalid[b] = #valid
// grid (EMBED/256, B, 32 j-chunks of 64), block 256. atomicAdd accumulate.
// ---------------------------------------------------------------------------
__global__ void vsum_kernel(const float* __restrict__ v, const int* __restrict__ mask,
                            float* __restrict__ vsum, float* __restrict__ nvalid) {
    int e  = blockIdx.x * 256 + threadIdx.x;   // 0..511
    int b  = blockIdx.y;
    int jc = blockIdx.z;                        // 0..31
    int jstart = jc * 64;
    const float* vb = v + ((size_t)b * SLEN + jstart) * EMBED + e;
    const int*   mb = mask + b * SLEN + jstart;
    float s = 0.f; int cnt = 0;
    #pragma unroll 4
    for (int j = 0; j < 64; ++j) {
        if (mb[j] != 0) { s += vb[(size_t)j * EMBED]; cnt++; }
    }
    atomicAdd(&vsum[b * EMBED + e], s);
    if (e == 0) atomicAdd(&nvalid[b], (float)cnt);
}

// ---------------------------------------------------------------------------
// Kernel 2: global attention for output row 0. One wave per (b,h).
// Reference applies NO mask and NO band here: plain softmax over all 2048 keys.
// ---------------------------------------------------------------------------
__global__ __launch_bounds__(64) void global_attn(
    const float* __restrict__ q, const float* __restrict__ k,
    const float* __restrict__ v, float* __restrict__ attn) {
    int h = blockIdx.x, b = blockIdx.y;
    int lane = threadIdx.x;
    __shared__ float qs[HDIM];
    __shared__ float w[SLEN];
    qs[lane] = q[((size_t)b * SLEN + 0) * EMBED + h * HDIM + lane];
    __syncthreads();
    const float* kb = k + (size_t)b * SLEN * EMBED + h * HDIM;
    float ssum = 0.f;
    for (int j = lane; j < SLEN; j += 64) {
        const float* kr = kb + (size_t)j * EMBED;
        float dot = 0.f;
        #pragma unroll
        for (int d = 0; d < HDIM; d += 4) {
            float4 kv = *(const float4*)(kr + d);
            dot += qs[d] * kv.x + qs[d + 1] * kv.y + qs[d + 2] * kv.z + qs[d + 3] * kv.w;
        }
        float e = __expf(dot * INV_SCALE);
        w[j] = e;
        ssum += e;
    }
    #pragma unroll
    for (int off = 32; off > 0; off >>= 1) ssum += __shfl_xor(ssum, off, 64);
    __syncthreads();
    const float* vb = v + (size_t)b * SLEN * EMBED + h * HDIM + lane;
    float num = 0.f;
    for (int j = 0; j < SLEN; ++j) num += w[j] * vb[(size_t)j * EMBED];
    attn[((size_t)b * SLEN + 0) * EMBED + h * HDIM + lane] = num / ssum;
}

// ---------------------------------------------------------------------------
// Kernel 3: windowed attention, output rows 1..2047.
// Block = 512 threads (8 waves), wave w handles head w. blockIdx.x = i = r-1.
// weight_j = exp(e/scale)-1 for in-band valid keys; denom = nvalid + sum(w);
// num_d = vsum_d + sum(w_j * v_j_d).
// ---------------------------------------------------------------------------
__global__ __launch_bounds__(512) void windowed_attn(
    const float* __restrict__ q, const float* __restrict__ k,
    const float* __restrict__ v, const int* __restrict__ mask,
    const float* __restrict__ vsum, const float* __restrict__ nvalid,
    float* __restrict__ attn) {
    int i = blockIdx.x;           // band center, 0..2046
    int b = blockIdx.y;
    int r = i + 1;                // output row
    int h = threadIdx.x >> 6;
    int lane = threadIdx.x & 63;
    int j0 = i - HALFW; if (j0 < 0) j0 = 0;
    int j1 = i + HALFW; if (j1 > SLEN - 1) j1 = SLEN - 1;
    int nk = j1 - j0 + 1;         // <= 257

    __shared__ float qs[HEADS][HDIM];
    __shared__ float wts[HEADS][264];

    qs[h][lane] = q[((size_t)b * SLEN + r) * EMBED + h * HDIM + lane];
    __syncthreads();

    const float* kb = k + (size_t)b * SLEN * EMBED + h * HDIM;
    const int*   mb = mask + b * SLEN;
    float ssum = 0.f;
    for (int idx = lane; idx < nk; idx += 64) {
        int j = j0 + idx;
        const float* kr = kb + (size_t)j * EMBED;
        float dot = 0.f;
        #pragma unroll
        for (int d = 0; d < HDIM; d += 4) {
            float4 kv = *(const float4*)(kr + d);
            dot += qs[h][d] * kv.x + qs[h][d + 1] * kv.y + qs[h][d + 2] * kv.z + qs[h][d + 3] * kv.w;
        }
        float wj = (mb[j] != 0) ? (__expf(dot * INV_SCALE) - 1.f) : 0.f;
        wts[h][idx] = wj;
        ssum += wj;
    }
    #pragma unroll
    for (int off = 32; off > 0; off >>= 1) ssum += __shfl_xor(ssum, off, 64);
    __syncthreads();

    float denom = nvalid[b] + ssum;
    const float* vb = v + (size_t)b * SLEN * EMBED + h * HDIM + lane;
    float num = 0.f;
    for (int idx = 0; idx < nk; ++idx) {
        num += wts[h][idx] * vb[(size_t)(j0 + idx) * EMBED];
    }
    attn[((size_t)b * SLEN + r) * EMBED + h * HDIM + lane] =
        (num + vsum[b * EMBED + h * HDIM + lane]) / denom;
}

// ---------------------------------------------------------------------------
// Kernel 4: FC.  C[m][n] = sum_k A[m][k]*W[n][k] + bias[n]
// M=4096, N=512, K=512. BM=BN=64, BK=16, 256 threads, 4x4 per thread.
// ---------------------------------------------------------------------------
__global__ __launch_bounds__(256) void fc_gemm(
    const float* __restrict__ A, const float* __restrict__ W,
    const float* __restrict__ bias, float* __restrict__ C) {
    __shared__ float As[16][68];  // [k][m], padded, 16B-aligned rows
    __shared__ float Ws[16][68];  // [k][n]
    int m0 = blockIdx.x * 64;
    int n0 = blockIdx.y * 64;
    int tx = threadIdx.x & 15, ty = threadIdx.x >> 4;
    float acc[4][4] = {};
    for (int k0 = 0; k0 < 512; k0 += 16) {
        int tm = threadIdx.x >> 2;          // 0..63
        int tk = (threadIdx.x & 3) * 4;     // 0,4,8,12
        float4 a4 = *(const float4*)(A + (size_t)(m0 + tm) * 512 + k0 + tk);
        As[tk + 0][tm] = a4.x; As[tk + 1][tm] = a4.y;
        As[tk + 2][tm] = a4.z; As[tk + 3][tm] = a4.w;
        float4 w4 = *(const float4*)(W + (size_t)(n0 + tm) * 512 + k0 + tk);
        Ws[tk + 0][tm] = w4.x; Ws[tk + 1][tm] = w4.y;
        Ws[tk + 2][tm] = w4.z; Ws[tk + 3][tm] = w4.w;
        __syncthreads();
        #pragma unroll
        for (int kk = 0; kk < 16; ++kk) {
            float4 av = *(const float4*)&As[kk][ty * 4];
            float4 wv = *(const float4*)&Ws[kk][tx * 4];
            float a[4] = {av.x, av.y, av.z, av.w};
            float w[4] = {wv.x, wv.y, wv.z, wv.w};
            #pragma unroll
            for (int x = 0; x < 4; ++x)
                #pragma unroll
                for (int y = 0; y < 4; ++y) acc[x][y] += a[x] * w[y];
        }
        __syncthreads();
    }
    #pragma unroll
    for (int x = 0; x < 4; ++x) {
        int m = m0 + ty * 4 + x;
        float4 o;
        o.x = acc[x][0] + bias[n0 + tx * 4 + 0];
        o.y = acc[x][1] + bias[n0 + tx * 4 + 1];
        o.z = acc[x][2] + bias[n0 + tx * 4 + 2];
        o.w = acc[x][3] + bias[n0 + tx * 4 + 3];
        *(float4*)(C + (size_t)m * 512 + n0 + tx * 4) = o;
    }
}

// ---------------------------------------------------------------------------
extern "C" void kernel_launch(void* const* d_in, const int* in_sizes, int n_in,
                              void* d_out, int out_size, void* d_ws, size_t ws_size,
                              hipStream_t stream) {
    const float* values = (const float*)d_in[0];
    const float* keys   = (const float*)d_in[1];
    const float* query  = (const float*)d_in[2];
    const int*   mask   = (const int*)d_in[3];
    const float* fc_w   = (const float*)d_in[4];
    const float* fc_b   = (const float*)d_in[5];
    float* out  = (float*)d_out;

    float* attn   = (float*)d_ws;                          // B*S*EMBED floats (8 MB)
    float* vsum   = attn + (size_t)BATCH * SLEN * EMBED;   // B*EMBED floats
    float* nvalid = vsum + BATCH * EMBED;                  // B floats

    hipMemsetAsync(vsum, 0, (BATCH * EMBED + BATCH) * sizeof(float), stream);

    vsum_kernel<<<dim3(EMBED / 256, BATCH, SLEN / 64), 256, 0, stream>>>(values, mask, vsum, nvalid);
    global_attn<<<dim3(HEADS, BATCH), 64, 0, stream>>>(query, keys, values, attn);
    windowed_attn<<<dim3(SLEN - 1, BATCH), 512, 0, stream>>>(query, keys, values, mask, vsum, nvalid, attn);
    fc_gemm<<<dim3(4096 / 64, 512 / 64), 256, 0, stream>>>(attn, fc_w, fc_b, out);
}

// Round 2
// 261.257 us; speedup vs baseline: 2.4655x; 2.4655x over previous
//
#include <hip/hip_runtime.h>
#include <math.h>

#define EMBED 512
#define HEADS 8
#define HDIM 64
#define SLEN 2048
#define BATCH 2
#define HALFW 128
#define INV_SCALE 0.044194173824159216f  // 1/sqrt(512)

// ---------------------------------------------------------------------------
// Kernel 1: vsum[b][e] = sum over valid j of v[b][j][e]; nvalid[b] = #valid
// ---------------------------------------------------------------------------
__global__ void vsum_kernel(const float* __restrict__ v, const int* __restrict__ mask,
                            float* __restrict__ vsum, float* __restrict__ nvalid) {
    int e  = blockIdx.x * 256 + threadIdx.x;   // 0..511
    int b  = blockIdx.y;
    int jc = blockIdx.z;                        // 0..31
    int jstart = jc * 64;
    const float* vb = v + ((size_t)b * SLEN + jstart) * EMBED + e;
    const int*   mb = mask + b * SLEN + jstart;
    float s = 0.f; int cnt = 0;
    #pragma unroll 4
    for (int j = 0; j < 64; ++j) {
        if (mb[j] != 0) { s += vb[(size_t)j * EMBED]; cnt++; }
    }
    atomicAdd(&vsum[b * EMBED + e], s);
    if (e == 0) atomicAdd(&nvalid[b], (float)cnt);
}

// ---------------------------------------------------------------------------
// Kernel 2: global attention, output row 0. One block (256 thr) per (h,b).
// Plain softmax over all 2048 keys (reference applies no mask/band here).
// ---------------------------------------------------------------------------
__global__ __launch_bounds__(256) void global_attn_v2(
    const float* __restrict__ q, const float* __restrict__ k,
    const float* __restrict__ v, float* __restrict__ attn) {
    int h = blockIdx.x, b = blockIdx.y;
    int t = threadIdx.x, w = t >> 6, l = t & 63;
    __shared__ float qs[HDIM];
    __shared__ float wbuf[SLEN];
    __shared__ float ssum_red[4];
    __shared__ float pv_red[4][HDIM];

    if (t < HDIM) qs[t] = q[(size_t)b * SLEN * EMBED + h * HDIM + t];
    __syncthreads();

    float ss = 0.f;
    for (int j = t; j < SLEN; j += 256) {
        const float* kr = k + ((size_t)b * SLEN + j) * EMBED + h * HDIM;
        float dot = 0.f;
        #pragma unroll
        for (int dq = 0; dq < 16; ++dq) {
            float4 k4 = *(const float4*)(kr + dq * 4);
            dot += qs[dq*4+0]*k4.x + qs[dq*4+1]*k4.y + qs[dq*4+2]*k4.z + qs[dq*4+3]*k4.w;
        }
        float e = __expf(dot * INV_SCALE);
        wbuf[j] = e;
        ss += e;
    }
    #pragma unroll
    for (int off = 32; off > 0; off >>= 1) ss += __shfl_xor(ss, off, 64);
    if (l == 0) ssum_red[w] = ss;
    __syncthreads();
    float denom = ssum_red[0] + ssum_red[1] + ssum_red[2] + ssum_red[3];

    // PV: wave w covers j in [w*512, (w+1)*512), lane = d
    float num = 0.f;
    const float* vb = v + (size_t)b * SLEN * EMBED + h * HDIM + l;
    #pragma unroll 8
    for (int j = w * 512; j < (w + 1) * 512; ++j) num += wbuf[j] * vb[(size_t)j * EMBED];
    pv_red[w][l] = num;
    __syncthreads();
    if (w == 0) {
        float o = (pv_red[0][l] + pv_red[1][l] + pv_red[2][l] + pv_red[3][l]) / denom;
        attn[(size_t)b * SLEN * EMBED + h * HDIM + l] = o;
    }
}

// ---------------------------------------------------------------------------
// Kernel 3: windowed attention v2 — 64-row query tile per block, one head.
// grid (32 tiles, 8 heads, 2 batch), block 256 (4 waves).
// Streams the key band in 64-key chunks through LDS.
//   QK phase: lane = row (q in 64 VGPRs), K read as LDS broadcasts (free).
//   PV phase: lane = d, 16 row-accumulators in regs, w read as b128 broadcast.
// weight = exp(z)-1 in band&valid else 0;  denom = nvalid + sum(w);
// out = (vsum + sum(w*v)) / denom.   No softmax-max needed: |z| <= ~2.
// ---------------------------------------------------------------------------
__global__ __launch_bounds__(256) void windowed_attn_v2(
    const float* __restrict__ q, const float* __restrict__ k,
    const float* __restrict__ v, const int* __restrict__ mask,
    const float* __restrict__ vsum, const float* __restrict__ nvalid,
    float* __restrict__ attn) {
    int tile = blockIdx.x;      // 0..31
    int h = blockIdx.y;
    int b = blockIdx.z;
    int r0 = tile * 64;
    int t = threadIdx.x;
    int w = t >> 6, l = t & 63;

    __shared__ float k_lds[64][64];      // [j][d] linear
    __shared__ float v_lds[64][64];      // [j][d] linear
    __shared__ float qw_lds[64][68];     // q staging, then scores w [row][j] (pad 68, 16B-aligned rows)
    __shared__ int   m_lds[64];
    __shared__ float red[4][64];

    // ---- stage q (coalesced) then move to regs (lane = row) ----
    #pragma unroll
    for (int p = 0; p < 4; ++p) {
        int idx = p * 256 + t;           // 1024 float4s = 64 rows x 16
        int row = idx >> 4, dq = idx & 15;
        float4 q4 = *(const float4*)(q + ((size_t)b * SLEN + r0 + row) * EMBED + h * HDIM + dq * 4);
        *(float4*)(&qw_lds[row][dq * 4]) = q4;
    }
    __syncthreads();
    float qreg[64];
    #pragma unroll
    for (int dq = 0; dq < 16; ++dq) {
        float4 q4 = *(const float4*)(&qw_lds[l][dq * 4]);
        qreg[dq*4+0] = q4.x; qreg[dq*4+1] = q4.y; qreg[dq*4+2] = q4.z; qreg[dq*4+3] = q4.w;
    }
    __syncthreads();   // qw_lds now reusable for scores

    int i_row = r0 + l - 1;              // band center for this lane's row (QK role)
    int j0 = r0 - 129; if (j0 < 0) j0 = 0;
    int j1 = r0 + 190; if (j1 > SLEN - 1) j1 = SLEN - 1;
    int nchunk = (j1 - j0 + 1 + 63) >> 6;

    float acc[16];
    #pragma unroll
    for (int ri = 0; ri < 16; ++ri) acc[ri] = 0.f;
    float wacc = 0.f;                    // lane=row partial denom (this wave's j's)

    for (int c = 0; c < nchunk; ++c) {
        int jc = j0 + c * 64;
        // ---- stage K,V chunk (zero-fill beyond j1) ----
        #pragma unroll
        for (int p = 0; p < 4; ++p) {
            int idx = p * 256 + t;       // 1024 float4s
            int jloc = idx >> 4, dq = idx & 15;
            int jj = jc + jloc;
            float4 k4 = make_float4(0.f, 0.f, 0.f, 0.f);
            float4 v4 = make_float4(0.f, 0.f, 0.f, 0.f);
            if (jj <= j1) {
                k4 = *(const float4*)(k + ((size_t)b * SLEN + jj) * EMBED + h * HDIM + dq * 4);
                v4 = *(const float4*)(v + ((size_t)b * SLEN + jj) * EMBED + h * HDIM + dq * 4);
            }
            *(float4*)(&k_lds[jloc][dq * 4]) = k4;
            *(float4*)(&v_lds[jloc][dq * 4]) = v4;
        }
        if (t < 64) {
            int jj = jc + t;
            m_lds[t] = (jj <= j1) ? mask[b * SLEN + jj] : 0;
        }
        __syncthreads();

        // ---- QK: lane = row, wave w covers jloc in [w*16, w*16+16) ----
        float wv[16];
        #pragma unroll
        for (int jl = 0; jl < 16; ++jl) {
            int jloc = w * 16 + jl;
            int jj = jc + jloc;
            float s = 0.f;
            #pragma unroll
            for (int dq = 0; dq < 16; ++dq) {
                float4 k4 = *(const float4*)(&k_lds[jloc][dq * 4]);   // broadcast
                s += qreg[dq*4+0]*k4.x + qreg[dq*4+1]*k4.y + qreg[dq*4+2]*k4.z + qreg[dq*4+3]*k4.w;
            }
            bool band = (jj >= i_row - HALFW) && (jj <= i_row + HALFW);
            float wj = (band && m_lds[jloc]) ? (__expf(s * INV_SCALE) - 1.f) : 0.f;
            wv[jl] = wj;
            wacc += wj;
        }
        #pragma unroll
        for (int jl = 0; jl < 16; ++jl) qw_lds[l][w * 16 + jl] = wv[jl];
        __syncthreads();

        // ---- PV: lane = d, wave w covers rows [w*16, w*16+16) ----
        #pragma unroll
        for (int jq = 0; jq < 16; ++jq) {
            float v0 = v_lds[jq*4+0][l];
            float v1 = v_lds[jq*4+1][l];
            float v2 = v_lds[jq*4+2][l];
            float v3 = v_lds[jq*4+3][l];
            #pragma unroll
            for (int ri = 0; ri < 16; ++ri) {
                float4 w4 = *(const float4*)(&qw_lds[w * 16 + ri][jq * 4]);  // broadcast
                acc[ri] += w4.x * v0 + w4.y * v1 + w4.z * v2 + w4.w * v3;
            }
        }
        __syncthreads();   // protect k/v/w before next chunk restage
    }

    red[w][l] = wacc;
    __syncthreads();

    // ---- epilogue: thread (w,l): d = l, rows w*16 + ri ----
    float nv = nvalid[b];
    float vs = vsum[b * EMBED + h * HDIM + l];
    #pragma unroll
    for (int ri = 0; ri < 16; ++ri) {
        int row = w * 16 + ri;
        int r = r0 + row;
        float den = nv + red[0][row] + red[1][row] + red[2][row] + red[3][row];
        float o = (acc[ri] + vs) / den;
        if (r != 0) attn[((size_t)b * SLEN + r) * EMBED + h * HDIM + l] = o;
    }
}

// ---------------------------------------------------------------------------
// Kernel 4: FC.  C[m][n] = sum_k A[m][k]*W[n][k] + bias[n]
// M=4096, N=512, K=512. BM=BN=64, BK=16, 256 threads, 4x4 per thread.
// ---------------------------------------------------------------------------
__global__ __launch_bounds__(256) void fc_gemm(
    const float* __restrict__ A, const float* __restrict__ W,
    const float* __restrict__ bias, float* __restrict__ C) {
    __shared__ float As[16][68];
    __shared__ float Ws[16][68];
    int m0 = blockIdx.x * 64;
    int n0 = blockIdx.y * 64;
    int tx = threadIdx.x & 15, ty = threadIdx.x >> 4;
    float acc[4][4] = {};
    for (int k0 = 0; k0 < 512; k0 += 16) {
        int tm = threadIdx.x >> 2;
        int tk = (threadIdx.x & 3) * 4;
        float4 a4 = *(const float4*)(A + (size_t)(m0 + tm) * 512 + k0 + tk);
        As[tk + 0][tm] = a4.x; As[tk + 1][tm] = a4.y;
        As[tk + 2][tm] = a4.z; As[tk + 3][tm] = a4.w;
        float4 w4 = *(const float4*)(W + (size_t)(n0 + tm) * 512 + k0 + tk);
        Ws[tk + 0][tm] = w4.x; Ws[tk + 1][tm] = w4.y;
        Ws[tk + 2][tm] = w4.z; Ws[tk + 3][tm] = w4.w;
        __syncthreads();
        #pragma unroll
        for (int kk = 0; kk < 16; ++kk) {
            float4 av = *(const float4*)&As[kk][ty * 4];
            float4 wv = *(const float4*)&Ws[kk][tx * 4];
            float a[4] = {av.x, av.y, av.z, av.w};
            float w[4] = {wv.x, wv.y, wv.z, wv.w};
            #pragma unroll
            for (int x = 0; x < 4; ++x)
                #pragma unroll
                for (int y = 0; y < 4; ++y) acc[x][y] += a[x] * w[y];
        }
        __syncthreads();
    }
    #pragma unroll
    for (int x = 0; x < 4; ++x) {
        int m = m0 + ty * 4 + x;
        float4 o;
        o.x = acc[x][0] + bias[n0 + tx * 4 + 0];
        o.y = acc[x][1] + bias[n0 + tx * 4 + 1];
        o.z = acc[x][2] + bias[n0 + tx * 4 + 2];
        o.w = acc[x][3] + bias[n0 + tx * 4 + 3];
        *(float4*)(C + (size_t)m * 512 + n0 + tx * 4) = o;
    }
}

// ---------------------------------------------------------------------------
extern "C" void kernel_launch(void* const* d_in, const int* in_sizes, int n_in,
                              void* d_out, int out_size, void* d_ws, size_t ws_size,
                              hipStream_t stream) {
    const float* values = (const float*)d_in[0];
    const float* keys   = (const float*)d_in[1];
    const float* query  = (const float*)d_in[2];
    const int*   mask   = (const int*)d_in[3];
    const float* fc_w   = (const float*)d_in[4];
    const float* fc_b   = (const float*)d_in[5];
    float* out  = (float*)d_out;

    float* attn   = (float*)d_ws;                          // B*S*EMBED floats (8 MB)
    float* vsum   = attn + (size_t)BATCH * SLEN * EMBED;   // B*EMBED floats
    float* nvalid = vsum + BATCH * EMBED;                  // B floats

    hipMemsetAsync(vsum, 0, (BATCH * EMBED + BATCH) * sizeof(float), stream);

    vsum_kernel<<<dim3(EMBED / 256, BATCH, SLEN / 64), 256, 0, stream>>>(values, mask, vsum, nvalid);
    global_attn_v2<<<dim3(HEADS, BATCH), 256, 0, stream>>>(query, keys, values, attn);
    windowed_attn_v2<<<dim3(SLEN / 64, HEADS, BATCH), 256, 0, stream>>>(query, keys, values, mask, vsum, nvalid, attn);
    fc_gemm<<<dim3(4096 / 64, 512 / 64), 256, 0, stream>>>(attn, fc_w, fc_b, out);
}

// Round 3
// 117.881 us; speedup vs baseline: 5.4644x; 2.2163x over previous
//
#include <hip/hip_runtime.h>
#include <math.h>

#define EMBED 512
#define HEADS 8
#define HDIM 64
#define SLEN 2048
#define BATCH 2
#define HALFW 128
#define INV_SCALE 0.044194173824159216f  // 1/sqrt(512)

typedef short bf16x8 __attribute__((ext_vector_type(8)));
typedef short s16x4  __attribute__((ext_vector_type(4)));
typedef float f32x4  __attribute__((ext_vector_type(4)));

#define MFMA16(a, b, c) __builtin_amdgcn_mfma_f32_16x16x32_bf16(a, b, c, 0, 0, 0)

__device__ __forceinline__ short f2bf(float x) {
    union { float f; unsigned u; } v; v.f = x;
    unsigned r = v.u + 0x7FFFu + ((v.u >> 16) & 1u);  // RNE
    return (short)(r >> 16);
}

// Blocked-frag LDS layout for a 64x64 bf16 tile, XOR-swizzled:
// 16B fragment (row, seg) lives at short index ((seg*64) + (row^seg)) * 8.
// Element (row, kd) -> lidx(row, kd>>3) + (kd&7).
// Derived properties (see session notes): MFMA frag reads (16 lanes = 16 rows,
// same seg), staging writes (16 lanes = same row, 16 segs OR same seg, 16 rows)
// are ALL bank-conflict-free.
__device__ __forceinline__ int lidx(int row, int seg) {
    return (((seg << 6) + (row ^ seg)) << 3);
}

// ---------------------------------------------------------------------------
// Kernel 1: vsum[b][e] = sum over valid j of v[b][j][e]; nvalid[b] = #valid
// ---------------------------------------------------------------------------
__global__ void vsum_kernel(const float* __restrict__ v, const int* __restrict__ mask,
                            float* __restrict__ vsum, float* __restrict__ nvalid) {
    int e  = blockIdx.x * 256 + threadIdx.x;
    int b  = blockIdx.y;
    int jc = blockIdx.z;
    int jstart = jc * 64;
    const float* vb = v + ((size_t)b * SLEN + jstart) * EMBED + e;
    const int*   mb = mask + b * SLEN + jstart;
    float s = 0.f; int cnt = 0;
    #pragma unroll 4
    for (int j = 0; j < 64; ++j) {
        if (mb[j] != 0) { s += vb[(size_t)j * EMBED]; cnt++; }
    }
    atomicAdd(&vsum[b * EMBED + e], s);
    if (e == 0) atomicAdd(&nvalid[b], (float)cnt);
}

// ---------------------------------------------------------------------------
// Kernel 2: fc_w fp32 -> bf16
// ---------------------------------------------------------------------------
__global__ __launch_bounds__(256) void wcvt(const float* __restrict__ w,
                                            short* __restrict__ wbf) {
    int idx = blockIdx.x * 256 + threadIdx.x;       // 0..65535 float4s
    float4 f = ((const float4*)w)[idx];
    s16x4 o;
    o[0] = f2bf(f.x); o[1] = f2bf(f.y); o[2] = f2bf(f.z); o[3] = f2bf(f.w);
    ((s16x4*)wbf)[idx] = o;
}

// ---------------------------------------------------------------------------
// Kernel 3: global attention, output row 0 (plain softmax over all keys).
// ---------------------------------------------------------------------------
__global__ __launch_bounds__(256) void global_attn_v3(
    const float* __restrict__ q, const float* __restrict__ k,
    const float* __restrict__ v, short* __restrict__ attn) {
    int h = blockIdx.x, b = blockIdx.y;
    int t = threadIdx.x, w = t >> 6, l = t & 63;
    __shared__ float qs[HDIM];
    __shared__ float wbuf[SLEN];
    __shared__ float ssum_red[4];
    __shared__ float pv_red[4][HDIM];

    if (t < HDIM) qs[t] = q[(size_t)b * SLEN * EMBED + h * HDIM + t];
    __syncthreads();

    float ss = 0.f;
    for (int j = t; j < SLEN; j += 256) {
        const float* kr = k + ((size_t)b * SLEN + j) * EMBED + h * HDIM;
        float dot = 0.f;
        #pragma unroll
        for (int dq = 0; dq < 16; ++dq) {
            float4 k4 = *(const float4*)(kr + dq * 4);
            dot += qs[dq*4+0]*k4.x + qs[dq*4+1]*k4.y + qs[dq*4+2]*k4.z + qs[dq*4+3]*k4.w;
        }
        float e = __expf(dot * INV_SCALE);
        wbuf[j] = e;
        ss += e;
    }
    #pragma unroll
    for (int off = 32; off > 0; off >>= 1) ss += __shfl_xor(ss, off, 64);
    if (l == 0) ssum_red[w] = ss;
    __syncthreads();
    float denom = ssum_red[0] + ssum_red[1] + ssum_red[2] + ssum_red[3];

    float num = 0.f;
    const float* vb = v + (size_t)b * SLEN * EMBED + h * HDIM + l;
    #pragma unroll 8
    for (int j = w * 512; j < (w + 1) * 512; ++j) num += wbuf[j] * vb[(size_t)j * EMBED];
    pv_red[w][l] = num;
    __syncthreads();
    if (w == 0) {
        float o = (pv_red[0][l] + pv_red[1][l] + pv_red[2][l] + pv_red[3][l]) / denom;
        attn[(size_t)b * SLEN * EMBED + h * HDIM + l] = f2bf(o);
    }
}

// ---------------------------------------------------------------------------
// Kernel 4: windowed attention v3 — MFMA bf16.
// Block: 256 thr (4 waves), 64-row query tile, one head. 5 chunks of 64 keys.
// Wave w owns output rows [w*16, w*16+16).
//   QK^T: A = Q rows (bf16 frags, preloaded), B = K^T from k_s; D = scores.
//   elementwise: w = band&&mask ? exp(z)-1 : 0; bf16 -> w_s; fp32 -> dsum.
//   PV: A = W from w_s, B = V from vT_s, accumulate f32x4 across chunks.
//   out = (pv + vsum) / (nvalid + rowsum(w)), written bf16.
// ---------------------------------------------------------------------------
__global__ __launch_bounds__(256) void windowed_attn_v3(
    const float* __restrict__ q, const float* __restrict__ k,
    const float* __restrict__ v, const int* __restrict__ mask,
    const float* __restrict__ vsum, const float* __restrict__ nvalid,
    short* __restrict__ attn) {
    int tile = blockIdx.x;
    int h = blockIdx.y;
    int b = blockIdx.z;
    int r0 = tile * 64;
    int t = threadIdx.x;
    int w = t >> 6, l = t & 63;
    int lg = l >> 4, lr = l & 15;

    __shared__ __align__(16) short q_s[4096];
    __shared__ __align__(16) short k_s[4096];
    __shared__ __align__(16) short vT_s[4096];   // stored as (row=d, kd=jloc)
    __shared__ __align__(16) short w_s[4096];
    __shared__ int m_s[64];

    // ---- stage Q (fp32 global, coalesced) -> bf16 blocked LDS ----
    #pragma unroll
    for (int p = 0; p < 4; ++p) {
        int idx = p * 256 + t;
        int row = idx >> 4, kg = idx & 15;
        float4 f = *(const float4*)(q + ((size_t)b * SLEN + r0 + row) * EMBED + h * HDIM + kg * 4);
        s16x4 o;
        o[0] = f2bf(f.x); o[1] = f2bf(f.y); o[2] = f2bf(f.z); o[3] = f2bf(f.w);
        *(s16x4*)&q_s[lidx(row, kg >> 1) + (kg & 1) * 4] = o;
    }
    __syncthreads();

    // Q A-frags for this wave's 16-row strip (k 0..31 and 32..63)
    bf16x8 qa0 = *(const bf16x8*)&q_s[lidx(w * 16 + lr, lg)];
    bf16x8 qa1 = *(const bf16x8*)&q_s[lidx(w * 16 + lr, 4 + lg)];

    int j0 = r0 - 129; if (j0 < 0) j0 = 0;
    int j1 = r0 + 190; if (j1 > SLEN - 1) j1 = SLEN - 1;

    float dsum[4] = {0.f, 0.f, 0.f, 0.f};
    f32x4 pv[4];
    #pragma unroll
    for (int dt = 0; dt < 4; ++dt) pv[dt] = (f32x4){0.f, 0.f, 0.f, 0.f};

    for (int jc = j0; jc <= j1; jc += 64) {
        // ---- stage K chunk ----
        #pragma unroll
        for (int p = 0; p < 4; ++p) {
            int idx = p * 256 + t;
            int row = idx >> 4, kg = idx & 15;
            int jj = jc + row;
            float4 f = make_float4(0.f, 0.f, 0.f, 0.f);
            if (jj <= j1)
                f = *(const float4*)(k + ((size_t)b * SLEN + jj) * EMBED + h * HDIM + kg * 4);
            s16x4 o;
            o[0] = f2bf(f.x); o[1] = f2bf(f.y); o[2] = f2bf(f.z); o[3] = f2bf(f.w);
            *(s16x4*)&k_s[lidx(row, kg >> 1) + (kg & 1) * 4] = o;
        }
        // ---- stage V chunk, transposed: vT_s(row=d, kd=jloc) ----
        #pragma unroll
        for (int p = 0; p < 4; ++p) {
            int jloc = p * 16 + (t >> 4);
            int dbase = t & 15;
            int jj = jc + jloc;
            const float* vr = v + ((size_t)b * SLEN + jj) * EMBED + h * HDIM;
            #pragma unroll
            for (int u = 0; u < 4; ++u) {
                int d = dbase + u * 16;
                float val = (jj <= j1) ? vr[d] : 0.f;
                vT_s[lidx(d, jloc >> 3) + (jloc & 7)] = f2bf(val);
            }
        }
        if (t < 64) {
            int jj = jc + t;
            m_s[t] = (jj <= j1) ? mask[b * SLEN + jj] : 0;
        }
        __syncthreads();

        // ---- QK^T: 4 key-tiles of 16 ----
        #pragma unroll
        for (int tc = 0; tc < 4; ++tc) {
            bf16x8 kb0 = *(const bf16x8*)&k_s[lidx(tc * 16 + lr, lg)];
            bf16x8 kb1 = *(const bf16x8*)&k_s[lidx(tc * 16 + lr, 4 + lg)];
            f32x4 s = (f32x4){0.f, 0.f, 0.f, 0.f};
            s = MFMA16(qa0, kb0, s);
            s = MFMA16(qa1, kb1, s);
            int jj = jc + tc * 16 + lr;     // this lane's key column
            int mok = m_s[tc * 16 + lr];
            #pragma unroll
            for (int reg = 0; reg < 4; ++reg) {
                int rowl = w * 16 + lg * 4 + reg;
                int center = r0 + rowl - 1;
                float wgt = 0.f;
                if (mok && jj >= center - HALFW && jj <= center + HALFW)
                    wgt = __expf(s[reg] * INV_SCALE) - 1.f;
                dsum[reg] += wgt;
                int kd = tc * 16 + lr;
                w_s[lidx(rowl, kd >> 3) + (kd & 7)] = f2bf(wgt);
            }
        }
        __syncthreads();

        // ---- PV: A = W strip, B = V^T ----
        bf16x8 wa0 = *(const bf16x8*)&w_s[lidx(w * 16 + lr, lg)];
        bf16x8 wa1 = *(const bf16x8*)&w_s[lidx(w * 16 + lr, 4 + lg)];
        #pragma unroll
        for (int dt = 0; dt < 4; ++dt) {
            bf16x8 vb0 = *(const bf16x8*)&vT_s[lidx(dt * 16 + lr, lg)];
            bf16x8 vb1 = *(const bf16x8*)&vT_s[lidx(dt * 16 + lr, 4 + lg)];
            pv[dt] = MFMA16(wa0, vb0, pv[dt]);
            pv[dt] = MFMA16(wa1, vb1, pv[dt]);
        }
        __syncthreads();
    }

    // ---- row-sum reduce for denominator (lanes same lg share rows) ----
    #pragma unroll
    for (int reg = 0; reg < 4; ++reg) {
        float d0 = dsum[reg];
        d0 += __shfl_xor(d0, 1, 64);
        d0 += __shfl_xor(d0, 2, 64);
        d0 += __shfl_xor(d0, 4, 64);
        d0 += __shfl_xor(d0, 8, 64);
        dsum[reg] = d0;
    }
    float nv = nvalid[b];
    float inv[4];
    #pragma unroll
    for (int reg = 0; reg < 4; ++reg) inv[reg] = 1.f / (nv + dsum[reg]);

    #pragma unroll
    for (int dt = 0; dt < 4; ++dt) {
        int d = dt * 16 + lr;
        float vs = vsum[b * EMBED + h * HDIM + d];
        #pragma unroll
        for (int reg = 0; reg < 4; ++reg) {
            int rowl = w * 16 + lg * 4 + reg;
            int r = r0 + rowl;
            float o = (pv[dt][reg] + vs) * inv[reg];
            if (r != 0)
                attn[((size_t)b * SLEN + r) * EMBED + h * HDIM + d] = f2bf(o);
        }
    }
}

// ---------------------------------------------------------------------------
// Kernel 5: FC GEMM, bf16 MFMA. C[m][n] = sum_k A[m][k]*W[n][k] + bias[n]
// M=4096 N=512 K=512. BM=BN=64, BK=64, 256 thr (4 waves as 2x2 of 32x32).
// ---------------------------------------------------------------------------
__global__ __launch_bounds__(256) void fc_gemm_v2(
    const short* __restrict__ A, const short* __restrict__ W,
    const float* __restrict__ bias, float* __restrict__ C) {
    __shared__ __align__(16) short a_s[4096];
    __shared__ __align__(16) short b_s[4096];
    int m0 = blockIdx.x * 64;
    int n0 = blockIdx.y * 64;
    int t = threadIdx.x;
    int w = t >> 6, l = t & 63;
    int lg = l >> 4, lr = l & 15;
    int wr = w >> 1, wc = w & 1;

    f32x4 c[2][2];
    #pragma unroll
    for (int mt = 0; mt < 2; ++mt)
        #pragma unroll
        for (int nt = 0; nt < 2; ++nt) c[mt][nt] = (f32x4){0.f, 0.f, 0.f, 0.f};

    for (int k0 = 0; k0 < 512; k0 += 64) {
        #pragma unroll
        for (int p = 0; p < 2; ++p) {
            int idx = p * 256 + t;
            int row = idx >> 3, sg = idx & 7;
            bf16x8 av = *(const bf16x8*)&A[(size_t)(m0 + row) * 512 + k0 + sg * 8];
            *(bf16x8*)&a_s[lidx(row, sg)] = av;
            bf16x8 bv = *(const bf16x8*)&W[(size_t)(n0 + row) * 512 + k0 + sg * 8];
            *(bf16x8*)&b_s[lidx(row, sg)] = bv;
        }
        __syncthreads();

        bf16x8 af[2][2], bf_[2][2];
        #pragma unroll
        for (int mt = 0; mt < 2; ++mt) {
            af[mt][0] = *(const bf16x8*)&a_s[lidx(wr * 32 + mt * 16 + lr, lg)];
            af[mt][1] = *(const bf16x8*)&a_s[lidx(wr * 32 + mt * 16 + lr, 4 + lg)];
        }
        #pragma unroll
        for (int nt = 0; nt < 2; ++nt) {
            bf_[nt][0] = *(const bf16x8*)&b_s[lidx(wc * 32 + nt * 16 + lr, lg)];
            bf_[nt][1] = *(const bf16x8*)&b_s[lidx(wc * 32 + nt * 16 + lr, 4 + lg)];
        }
        #pragma unroll
        for (int mt = 0; mt < 2; ++mt)
            #pragma unroll
            for (int nt = 0; nt < 2; ++nt) {
                c[mt][nt] = MFMA16(af[mt][0], bf_[nt][0], c[mt][nt]);
                c[mt][nt] = MFMA16(af[mt][1], bf_[nt][1], c[mt][nt]);
            }
        __syncthreads();
    }

    #pragma unroll
    for (int mt = 0; mt < 2; ++mt)
        #pragma unroll
        for (int nt = 0; nt < 2; ++nt) {
            int n = n0 + wc * 32 + nt * 16 + lr;
            float bb = bias[n];
            #pragma unroll
            for (int reg = 0; reg < 4; ++reg) {
                int m = m0 + wr * 32 + mt * 16 + lg * 4 + reg;
                C[(size_t)m * 512 + n] = c[mt][nt][reg] + bb;
            }
        }
}

// ---------------------------------------------------------------------------
extern "C" void kernel_launch(void* const* d_in, const int* in_sizes, int n_in,
                              void* d_out, int out_size, void* d_ws, size_t ws_size,
                              hipStream_t stream) {
    const float* values = (const float*)d_in[0];
    const float* keys   = (const float*)d_in[1];
    const float* query  = (const float*)d_in[2];
    const int*   mask   = (const int*)d_in[3];
    const float* fc_w   = (const float*)d_in[4];
    const float* fc_b   = (const float*)d_in[5];
    float* out = (float*)d_out;

    short* attn   = (short*)d_ws;                            // 4 MB bf16
    short* wbf    = attn + (size_t)BATCH * SLEN * EMBED;     // 0.5 MB bf16
    float* vsum   = (float*)(wbf + (size_t)EMBED * EMBED);   // 4 KB
    float* nvalid = vsum + BATCH * EMBED;

    hipMemsetAsync(vsum, 0, (BATCH * EMBED + BATCH) * sizeof(float), stream);

    vsum_kernel<<<dim3(EMBED / 256, BATCH, SLEN / 64), 256, 0, stream>>>(values, mask, vsum, nvalid);
    wcvt<<<dim3(256), 256, 0, stream>>>(fc_w, wbf);
    global_attn_v3<<<dim3(HEADS, BATCH), 256, 0, stream>>>(query, keys, values, attn);
    windowed_attn_v3<<<dim3(SLEN / 64, HEADS, BATCH), 256, 0, stream>>>(query, keys, values, mask, vsum, nvalid, attn);
    fc_gemm_v2<<<dim3(4096 / 64, 512 / 64), 256, 0, stream>>>(attn, wbf, fc_b, out);
}

// Round 4
// 66.417 us; speedup vs baseline: 9.6984x; 1.7749x over previous
//
#include <hip/hip_runtime.h>
#include <math.h>

#define EMBED 512
#define HEADS 8
#define HDIM 64
#define SLEN 2048
#define BATCH 2
#define HALFW 128
#define INV_SCALE 0.044194173824159216f  // 1/sqrt(512)

typedef short bf16x8 __attribute__((ext_vector_type(8)));
typedef short s16x4  __attribute__((ext_vector_type(4)));
typedef float f32x4  __attribute__((ext_vector_type(4)));

#define MFMA16(a, b, c) __builtin_amdgcn_mfma_f32_16x16x32_bf16(a, b, c, 0, 0, 0)

__device__ __forceinline__ short f2bf(float x) {
    union { float f; unsigned u; } v; v.f = x;
    unsigned r = v.u + 0x7FFFu + ((v.u >> 16) & 1u);  // RNE
    return (short)(r >> 16);
}

// Blocked-frag LDS layout for a 64x64 bf16 tile, XOR-swizzled:
// 16B fragment (row, seg) lives at short index ((seg*64) + (row^seg)) * 8.
// MFMA frag reads and staging writes are all bank-conflict-free.
__device__ __forceinline__ int lidx(int row, int seg) {
    return (((seg << 6) + (row ^ seg)) << 3);
}

// ---------------------------------------------------------------------------
// Kernel 1: fc_w fp32 -> bf16
// ---------------------------------------------------------------------------
__global__ __launch_bounds__(256) void wcvt(const float* __restrict__ w,
                                            short* __restrict__ wbf) {
    int idx = blockIdx.x * 256 + threadIdx.x;
    float4 f = ((const float4*)w)[idx];
    s16x4 o;
    o[0] = f2bf(f.x); o[1] = f2bf(f.y); o[2] = f2bf(f.z); o[3] = f2bf(f.w);
    ((s16x4*)wbf)[idx] = o;
}

// ---------------------------------------------------------------------------
// Kernel 2: row-0 global attention partials + fused vsum/nvalid partials.
// grid (32 j-chunks, HEADS, BATCH), block 256 (4 waves).
//   - partial denom: sum_j exp(q0 . k_j / scale)           -> gden[b][h]
//   - partial num_d: sum_j exp(.) * v[j][d]                -> gnum[b][h][d]
//   - partial vsum_e: sum_{j valid} v[j][e]  (e = h*64+d)  -> vsum[b][e]
//   - nvalid[b] (h==0 blocks only)
// ---------------------------------------------------------------------------
__global__ __launch_bounds__(256) void global_attn_partial(
    const float* __restrict__ q, const float* __restrict__ k,
    const float* __restrict__ v, const int* __restrict__ mask,
    float* __restrict__ gnum, float* __restrict__ gden,
    float* __restrict__ vsum, float* __restrict__ nvalid) {
    int jc = blockIdx.x, h = blockIdx.y, b = blockIdx.z;
    int j0 = jc * 64;
    int t = threadIdx.x, w = t >> 6, l = t & 63;

    __shared__ float qs[HDIM];
    __shared__ float wls[64];
    __shared__ int   m_s[64];
    __shared__ float red[4][HDIM];
    __shared__ float redv[4][HDIM];

    if (t < HDIM) qs[t] = q[(size_t)b * SLEN * EMBED + h * HDIM + t];
    if (t >= 64 && t < 128) m_s[t - 64] = mask[b * SLEN + j0 + (t - 64)];
    __syncthreads();

    // QK: thread t handles j = j0 + (t>>2), d-range (t&3)*16 .. +16
    int jl = t >> 2, dq0 = (t & 3) * 16;
    const float* kr = k + ((size_t)b * SLEN + j0 + jl) * EMBED + h * HDIM + dq0;
    float dot = 0.f;
    #pragma unroll
    for (int dq = 0; dq < 4; ++dq) {
        float4 k4 = *(const float4*)(kr + dq * 4);
        dot += qs[dq0 + dq*4 + 0] * k4.x + qs[dq0 + dq*4 + 1] * k4.y +
               qs[dq0 + dq*4 + 2] * k4.z + qs[dq0 + dq*4 + 3] * k4.w;
    }
    dot += __shfl_xor(dot, 1, 64);
    dot += __shfl_xor(dot, 2, 64);
    if ((t & 3) == 0) wls[jl] = __expf(dot * INV_SCALE);
    __syncthreads();

    // PV partial + vsum partial: wave w covers j [w*16, w*16+16), lane = d
    float num = 0.f, vs = 0.f;
    #pragma unroll
    for (int jj = 0; jj < 16; ++jj) {
        int jloc = w * 16 + jj;
        float vv = v[((size_t)b * SLEN + j0 + jloc) * EMBED + h * HDIM + l];
        num += wls[jloc] * vv;
        if (m_s[jloc]) vs += vv;
    }
    red[w][l] = num;
    redv[w][l] = vs;
    __syncthreads();

    if (w == 0) {
        atomicAdd(&gnum[((size_t)b * HEADS + h) * HDIM + l],
                  red[0][l] + red[1][l] + red[2][l] + red[3][l]);
        atomicAdd(&vsum[b * EMBED + h * HDIM + l],
                  redv[0][l] + redv[1][l] + redv[2][l] + redv[3][l]);
    } else if (w == 1) {
        float s = wls[l];
        #pragma unroll
        for (int off = 32; off > 0; off >>= 1) s += __shfl_xor(s, off, 64);
        if (l == 0) atomicAdd(&gden[b * HEADS + h], s);
    } else if (w == 2 && h == 0) {
        float c = (float)(m_s[l] != 0);
        #pragma unroll
        for (int off = 32; off > 0; off >>= 1) c += __shfl_xor(c, off, 64);
        if (l == 0) atomicAdd(&nvalid[b], c);
    }
}

// ---------------------------------------------------------------------------
// Kernel 3: finalize row 0: attn[b][0][h*64+d] = gnum/gden (bf16)
// ---------------------------------------------------------------------------
__global__ __launch_bounds__(1024) void global_attn_final(
    const float* __restrict__ gnum, const float* __restrict__ gden,
    short* __restrict__ attn) {
    int t = threadIdx.x;          // 0..1023 = (b*8+h)*64+d
    int bh = t >> 6, d = t & 63;
    int b = bh >> 3, h = bh & 7;
    float o = gnum[t] / gden[bh];
    attn[(size_t)b * SLEN * EMBED + h * HDIM + d] = f2bf(o);
}

// ---------------------------------------------------------------------------
// Kernel 4: windowed attention — MFMA bf16 (rows 1..2047).
// ---------------------------------------------------------------------------
__global__ __launch_bounds__(256) void windowed_attn_v3(
    const float* __restrict__ q, const float* __restrict__ k,
    const float* __restrict__ v, const int* __restrict__ mask,
    const float* __restrict__ vsum, const float* __restrict__ nvalid,
    short* __restrict__ attn) {
    int tile = blockIdx.x;
    int h = blockIdx.y;
    int b = blockIdx.z;
    int r0 = tile * 64;
    int t = threadIdx.x;
    int w = t >> 6, l = t & 63;
    int lg = l >> 4, lr = l & 15;

    __shared__ __align__(16) short q_s[4096];
    __shared__ __align__(16) short k_s[4096];
    __shared__ __align__(16) short vT_s[4096];   // (row=d, kd=jloc)
    __shared__ __align__(16) short w_s[4096];
    __shared__ int m_s[64];

    // ---- stage Q -> bf16 blocked LDS ----
    #pragma unroll
    for (int p = 0; p < 4; ++p) {
        int idx = p * 256 + t;
        int row = idx >> 4, kg = idx & 15;
        float4 f = *(const float4*)(q + ((size_t)b * SLEN + r0 + row) * EMBED + h * HDIM + kg * 4);
        s16x4 o;
        o[0] = f2bf(f.x); o[1] = f2bf(f.y); o[2] = f2bf(f.z); o[3] = f2bf(f.w);
        *(s16x4*)&q_s[lidx(row, kg >> 1) + (kg & 1) * 4] = o;
    }
    __syncthreads();

    bf16x8 qa0 = *(const bf16x8*)&q_s[lidx(w * 16 + lr, lg)];
    bf16x8 qa1 = *(const bf16x8*)&q_s[lidx(w * 16 + lr, 4 + lg)];

    int j0 = r0 - 129; if (j0 < 0) j0 = 0;
    int j1 = r0 + 190; if (j1 > SLEN - 1) j1 = SLEN - 1;

    float dsum[4] = {0.f, 0.f, 0.f, 0.f};
    f32x4 pv[4];
    #pragma unroll
    for (int dt = 0; dt < 4; ++dt) pv[dt] = (f32x4){0.f, 0.f, 0.f, 0.f};

    for (int jc = j0; jc <= j1; jc += 64) {
        #pragma unroll
        for (int p = 0; p < 4; ++p) {
            int idx = p * 256 + t;
            int row = idx >> 4, kg = idx & 15;
            int jj = jc + row;
            float4 f = make_float4(0.f, 0.f, 0.f, 0.f);
            if (jj <= j1)
                f = *(const float4*)(k + ((size_t)b * SLEN + jj) * EMBED + h * HDIM + kg * 4);
            s16x4 o;
            o[0] = f2bf(f.x); o[1] = f2bf(f.y); o[2] = f2bf(f.z); o[3] = f2bf(f.w);
            *(s16x4*)&k_s[lidx(row, kg >> 1) + (kg & 1) * 4] = o;
        }
        #pragma unroll
        for (int p = 0; p < 4; ++p) {
            int jloc = p * 16 + (t >> 4);
            int dbase = t & 15;
            int jj = jc + jloc;
            const float* vr = v + ((size_t)b * SLEN + jj) * EMBED + h * HDIM;
            #pragma unroll
            for (int u = 0; u < 4; ++u) {
                int d = dbase + u * 16;
                float val = (jj <= j1) ? vr[d] : 0.f;
                vT_s[lidx(d, jloc >> 3) + (jloc & 7)] = f2bf(val);
            }
        }
        if (t < 64) {
            int jj = jc + t;
            m_s[t] = (jj <= j1) ? mask[b * SLEN + jj] : 0;
        }
        __syncthreads();

        #pragma unroll
        for (int tc = 0; tc < 4; ++tc) {
            bf16x8 kb0 = *(const bf16x8*)&k_s[lidx(tc * 16 + lr, lg)];
            bf16x8 kb1 = *(const bf16x8*)&k_s[lidx(tc * 16 + lr, 4 + lg)];
            f32x4 s = (f32x4){0.f, 0.f, 0.f, 0.f};
            s = MFMA16(qa0, kb0, s);
            s = MFMA16(qa1, kb1, s);
            int jj = jc + tc * 16 + lr;
            int mok = m_s[tc * 16 + lr];
            #pragma unroll
            for (int reg = 0; reg < 4; ++reg) {
                int rowl = w * 16 + lg * 4 + reg;
                int center = r0 + rowl - 1;
                float wgt = 0.f;
                if (mok && jj >= center - HALFW && jj <= center + HALFW)
                    wgt = __expf(s[reg] * INV_SCALE) - 1.f;
                dsum[reg] += wgt;
                int kd = tc * 16 + lr;
                w_s[lidx(rowl, kd >> 3) + (kd & 7)] = f2bf(wgt);
            }
        }
        __syncthreads();

        bf16x8 wa0 = *(const bf16x8*)&w_s[lidx(w * 16 + lr, lg)];
        bf16x8 wa1 = *(const bf16x8*)&w_s[lidx(w * 16 + lr, 4 + lg)];
        #pragma unroll
        for (int dt = 0; dt < 4; ++dt) {
            bf16x8 vb0 = *(const bf16x8*)&vT_s[lidx(dt * 16 + lr, lg)];
            bf16x8 vb1 = *(const bf16x8*)&vT_s[lidx(dt * 16 + lr, 4 + lg)];
            pv[dt] = MFMA16(wa0, vb0, pv[dt]);
            pv[dt] = MFMA16(wa1, vb1, pv[dt]);
        }
        __syncthreads();
    }

    #pragma unroll
    for (int reg = 0; reg < 4; ++reg) {
        float d0 = dsum[reg];
        d0 += __shfl_xor(d0, 1, 64);
        d0 += __shfl_xor(d0, 2, 64);
        d0 += __shfl_xor(d0, 4, 64);
        d0 += __shfl_xor(d0, 8, 64);
        dsum[reg] = d0;
    }
    float nv = nvalid[b];
    float inv[4];
    #pragma unroll
    for (int reg = 0; reg < 4; ++reg) inv[reg] = 1.f / (nv + dsum[reg]);

    #pragma unroll
    for (int dt = 0; dt < 4; ++dt) {
        int d = dt * 16 + lr;
        float vs = vsum[b * EMBED + h * HDIM + d];
        #pragma unroll
        for (int reg = 0; reg < 4; ++reg) {
            int rowl = w * 16 + lg * 4 + reg;
            int r = r0 + rowl;
            float o = (pv[dt][reg] + vs) * inv[reg];
            if (r != 0)
                attn[((size_t)b * SLEN + r) * EMBED + h * HDIM + d] = f2bf(o);
        }
    }
}

// ---------------------------------------------------------------------------
// Kernel 5: FC GEMM, bf16 MFMA. M=4096 N=512 K=512. BM=BN=64, BK=64.
// ---------------------------------------------------------------------------
__global__ __launch_bounds__(256) void fc_gemm_v2(
    const short* __restrict__ A, const short* __restrict__ W,
    const float* __restrict__ bias, float* __restrict__ C) {
    __shared__ __align__(16) short a_s[4096];
    __shared__ __align__(16) short b_s[4096];
    int m0 = blockIdx.x * 64;
    int n0 = blockIdx.y * 64;
    int t = threadIdx.x;
    int w = t >> 6, l = t & 63;
    int lg = l >> 4, lr = l & 15;
    int wr = w >> 1, wc = w & 1;

    f32x4 c[2][2];
    #pragma unroll
    for (int mt = 0; mt < 2; ++mt)
        #pragma unroll
        for (int nt = 0; nt < 2; ++nt) c[mt][nt] = (f32x4){0.f, 0.f, 0.f, 0.f};

    for (int k0 = 0; k0 < 512; k0 += 64) {
        #pragma unroll
        for (int p = 0; p < 2; ++p) {
            int idx = p * 256 + t;
            int row = idx >> 3, sg = idx & 7;
            bf16x8 av = *(const bf16x8*)&A[(size_t)(m0 + row) * 512 + k0 + sg * 8];
            *(bf16x8*)&a_s[lidx(row, sg)] = av;
            bf16x8 bv = *(const bf16x8*)&W[(size_t)(n0 + row) * 512 + k0 + sg * 8];
            *(bf16x8*)&b_s[lidx(row, sg)] = bv;
        }
        __syncthreads();

        bf16x8 af[2][2], bf_[2][2];
        #pragma unroll
        for (int mt = 0; mt < 2; ++mt) {
            af[mt][0] = *(const bf16x8*)&a_s[lidx(wr * 32 + mt * 16 + lr, lg)];
            af[mt][1] = *(const bf16x8*)&a_s[lidx(wr * 32 + mt * 16 + lr, 4 + lg)];
        }
        #pragma unroll
        for (int nt = 0; nt < 2; ++nt) {
            bf_[nt][0] = *(const bf16x8*)&b_s[lidx(wc * 32 + nt * 16 + lr, lg)];
            bf_[nt][1] = *(const bf16x8*)&b_s[lidx(wc * 32 + nt * 16 + lr, 4 + lg)];
        }
        #pragma unroll
        for (int mt = 0; mt < 2; ++mt)
            #pragma unroll
            for (int nt = 0; nt < 2; ++nt) {
                c[mt][nt] = MFMA16(af[mt][0], bf_[nt][0], c[mt][nt]);
                c[mt][nt] = MFMA16(af[mt][1], bf_[nt][1], c[mt][nt]);
            }
        __syncthreads();
    }

    #pragma unroll
    for (int mt = 0; mt < 2; ++mt)
        #pragma unroll
        for (int nt = 0; nt < 2; ++nt) {
            int n = n0 + wc * 32 + nt * 16 + lr;
            float bb = bias[n];
            #pragma unroll
            for (int reg = 0; reg < 4; ++reg) {
                int m = m0 + wr * 32 + mt * 16 + lg * 4 + reg;
                C[(size_t)m * 512 + n] = c[mt][nt][reg] + bb;
            }
        }
}

// ---------------------------------------------------------------------------
extern "C" void kernel_launch(void* const* d_in, const int* in_sizes, int n_in,
                              void* d_out, int out_size, void* d_ws, size_t ws_size,
                              hipStream_t stream) {
    const float* values = (const float*)d_in[0];
    const float* keys   = (const float*)d_in[1];
    const float* query  = (const float*)d_in[2];
    const int*   mask   = (const int*)d_in[3];
    const float* fc_w   = (const float*)d_in[4];
    const float* fc_b   = (const float*)d_in[5];
    float* out = (float*)d_out;

    short* attn   = (short*)d_ws;                            // 4 MB bf16
    short* wbf    = attn + (size_t)BATCH * SLEN * EMBED;     // 0.5 MB bf16
    float* vsum   = (float*)(wbf + (size_t)EMBED * EMBED);   // B*EMBED
    float* nvalid = vsum + BATCH * EMBED;                    // B
    float* gnum   = nvalid + BATCH;                          // B*HEADS*HDIM
    float* gden   = gnum + BATCH * HEADS * HDIM;             // B*HEADS

    hipMemsetAsync(vsum, 0,
                   (BATCH * EMBED + BATCH + BATCH * HEADS * HDIM + BATCH * HEADS) * sizeof(float),
                   stream);

    wcvt<<<dim3(256), 256, 0, stream>>>(fc_w, wbf);
    global_attn_partial<<<dim3(SLEN / 64, HEADS, BATCH), 256, 0, stream>>>(
        query, keys, values, mask, gnum, gden, vsum, nvalid);
    global_attn_final<<<dim3(1), 1024, 0, stream>>>(gnum, gden, attn);
    windowed_attn_v3<<<dim3(SLEN / 64, HEADS, BATCH), 256, 0, stream>>>(
        query, keys, values, mask, vsum, nvalid, attn);
    fc_gemm_v2<<<dim3(4096 / 64, 512 / 64), 256, 0, stream>>>(attn, wbf, fc_b, out);
}

// Round 5
// 52.063 us; speedup vs baseline: 12.3724x; 1.2757x over previous
//
#include <hip/hip_runtime.h>
#include <math.h>

#define EMBED 512
#define HEADS 8
#define HDIM 64
#define SLEN 2048
#define BATCH 2
#define HALFW 128
#define NCHUNK 32
#define INV_SCALE 0.044194173824159216f  // 1/sqrt(512)

typedef short bf16x8 __attribute__((ext_vector_type(8)));
typedef short s16x4  __attribute__((ext_vector_type(4)));
typedef float f32x4  __attribute__((ext_vector_type(4)));

#define MFMA16(a, b, c) __builtin_amdgcn_mfma_f32_16x16x32_bf16(a, b, c, 0, 0, 0)

__device__ __forceinline__ short f2bf(float x) {
    union { float f; unsigned u; } v; v.f = x;
    unsigned r = v.u + 0x7FFFu + ((v.u >> 16) & 1u);  // RNE
    return (short)(r >> 16);
}

// Blocked-frag LDS/global layout for a 64x64 bf16 tile, XOR-swizzled:
// 16B fragment (row, seg) lives at short index ((seg*64) + (row^seg)) * 8.
// MFMA frag reads and staging writes are bank-conflict-free (verified R2/R3:
// SQ_LDS_BANK_CONFLICT == 0).
__device__ __forceinline__ int lidx(int row, int seg) {
    return (((seg << 6) + (row ^ seg)) << 3);
}

// async global->LDS, 16B per lane. dest: wave-uniform base, HW adds lane*16.
__device__ __forceinline__ void gll16(const short* g, short* l) {
    __builtin_amdgcn_global_load_lds(
        (const __attribute__((address_space(1))) unsigned int*)g,
        (__attribute__((address_space(3))) unsigned int*)l, 16, 0, 0);
}

// stage one 64x64 bf16 frag chunk (8KB) of K and V into LDS
__device__ __forceinline__ void stage_chunk(const short* Ksrc, const short* Vsrc,
                                            short* kbuf, short* vbuf, int t) {
    int off = t * 8;              // shorts: lane-linear, 16B each
    int wb  = (t >> 6) * 512;     // per-wave LDS base (shorts): w*1024 bytes
    gll16(Ksrc + off,        kbuf + wb);
    gll16(Ksrc + 2048 + off, kbuf + 2048 + wb);
    gll16(Vsrc + off,        vbuf + wb);
    gll16(Vsrc + 2048 + off, vbuf + 2048 + wb);
}

// ---------------------------------------------------------------------------
// Kernel 1: fc_w fp32 -> bf16
// ---------------------------------------------------------------------------
__global__ __launch_bounds__(256) void wcvt(const float* __restrict__ w,
                                            short* __restrict__ wbf) {
    int idx = blockIdx.x * 256 + threadIdx.x;
    float4 f = ((const float4*)w)[idx];
    s16x4 o;
    o[0] = f2bf(f.x); o[1] = f2bf(f.y); o[2] = f2bf(f.z); o[3] = f2bf(f.w);
    ((s16x4*)wbf)[idx] = o;
}

// ---------------------------------------------------------------------------
// Kernel 2: prepass. grid (32 chunks, HEADS, BATCH), 256 thr.
//  - Qbf/Kbf/Vbf: bf16 frag-layout conversion (Kbf rows zeroed where mask==0;
//    Vbf transposed to (d, j))
//  - row-0 global attention partials (gnum/gden, unmasked per reference)
//  - vsum (masked) / nvalid partials
// ---------------------------------------------------------------------------
__global__ __launch_bounds__(256) void prepass(
    const float* __restrict__ q, const float* __restrict__ k,
    const float* __restrict__ v, const int* __restrict__ mask,
    short* __restrict__ Qbf, short* __restrict__ Kbf, short* __restrict__ Vbf,
    float* __restrict__ gnum, float* __restrict__ gden,
    float* __restrict__ vsum, float* __restrict__ nvalid) {
    int c = blockIdx.x, h = blockIdx.y, b = blockIdx.z;
    int j0 = c * 64;
    int t = threadIdx.x, w = t >> 6, l = t & 63;

    __shared__ float q0s[HDIM];
    __shared__ float wls[64];
    __shared__ int   m_s[64];
    __shared__ float vbuf[64][68];
    __shared__ float red[4][HDIM];
    __shared__ float redv[4][HDIM];

    if (t < 64) {
        q0s[t] = q[(size_t)b * SLEN * EMBED + h * HDIM + t];
        m_s[t] = mask[b * SLEN + j0 + t];
    }
    __syncthreads();

    size_t fragbase = ((size_t)(b * HEADS + h) * NCHUNK + c) * 4096;

    // ---- Q tile -> Qbf frags ----
    #pragma unroll
    for (int p = 0; p < 4; ++p) {
        int idx = p * 256 + t, row = idx >> 4, kg = idx & 15;
        float4 f = *(const float4*)(q + ((size_t)b * SLEN + j0 + row) * EMBED + h * HDIM + kg * 4);
        s16x4 o;
        o[0] = f2bf(f.x); o[1] = f2bf(f.y); o[2] = f2bf(f.z); o[3] = f2bf(f.w);
        *(s16x4*)&Qbf[fragbase + lidx(row, kg >> 1) + (kg & 1) * 4] = o;
    }

    // ---- K chunk -> Kbf frags (masked rows zeroed) + row-0 dot ----
    #pragma unroll
    for (int p = 0; p < 4; ++p) {
        int idx = p * 256 + t, row = idx >> 4, kg = idx & 15;
        float4 f = *(const float4*)(k + ((size_t)b * SLEN + j0 + row) * EMBED + h * HDIM + kg * 4);
        float dot = q0s[kg*4+0]*f.x + q0s[kg*4+1]*f.y + q0s[kg*4+2]*f.z + q0s[kg*4+3]*f.w;
        dot += __shfl_xor(dot, 1, 64);
        dot += __shfl_xor(dot, 2, 64);
        dot += __shfl_xor(dot, 4, 64);
        dot += __shfl_xor(dot, 8, 64);
        if ((t & 15) == 0) wls[row] = __expf(dot * INV_SCALE);
        if (!m_s[row]) f = make_float4(0.f, 0.f, 0.f, 0.f);
        s16x4 o;
        o[0] = f2bf(f.x); o[1] = f2bf(f.y); o[2] = f2bf(f.z); o[3] = f2bf(f.w);
        *(s16x4*)&Kbf[fragbase + lidx(row, kg >> 1) + (kg & 1) * 4] = o;
    }

    // ---- V chunk -> LDS (fp32, padded) ----
    #pragma unroll
    for (int p = 0; p < 4; ++p) {
        int idx = p * 256 + t, row = idx >> 4, kg = idx & 15;
        float4 f = *(const float4*)(v + ((size_t)b * SLEN + j0 + row) * EMBED + h * HDIM + kg * 4);
        *(float4*)&vbuf[row][kg * 4] = f;
    }
    __syncthreads();

    // ---- row-0 PV + vsum partials: lane = d, wave w covers 16 j ----
    float num = 0.f, vs = 0.f;
    #pragma unroll
    for (int jj = 0; jj < 16; ++jj) {
        int jl = w * 16 + jj;
        float vv = vbuf[jl][l];
        num += wls[jl] * vv;
        if (m_s[jl]) vs += vv;
    }
    red[w][l] = num;
    redv[w][l] = vs;

    // ---- V -> Vbf transposed frags: thread (w,l): d=l, jseg = w*2+s ----
    #pragma unroll
    for (int s = 0; s < 2; ++s) {
        int jseg = w * 2 + s;
        bf16x8 o;
        #pragma unroll
        for (int e = 0; e < 8; ++e) o[e] = f2bf(vbuf[jseg * 8 + e][l]);
        *(bf16x8*)&Vbf[fragbase + lidx(l, jseg)] = o;
    }
    __syncthreads();

    if (w == 0) {
        atomicAdd(&gnum[((size_t)b * HEADS + h) * HDIM + l],
                  red[0][l] + red[1][l] + red[2][l] + red[3][l]);
        atomicAdd(&vsum[b * EMBED + h * HDIM + l],
                  redv[0][l] + redv[1][l] + redv[2][l] + redv[3][l]);
    } else if (w == 1) {
        float s = wls[l];
        #pragma unroll
        for (int off = 32; off > 0; off >>= 1) s += __shfl_xor(s, off, 64);
        if (l == 0) atomicAdd(&gden[b * HEADS + h], s);
    } else if (w == 2 && h == 0) {
        float cc = m_s[l] ? 1.f : 0.f;
        #pragma unroll
        for (int off = 32; off > 0; off >>= 1) cc += __shfl_xor(cc, off, 64);
        if (l == 0) atomicAdd(&nvalid[b], cc);
    }
}

// ---------------------------------------------------------------------------
// Kernel 3: finalize row 0
// ---------------------------------------------------------------------------
__global__ __launch_bounds__(1024) void global_attn_final(
    const float* __restrict__ gnum, const float* __restrict__ gden,
    short* __restrict__ attn) {
    int t = threadIdx.x;
    int bh = t >> 6, d = t & 63;
    int b = bh >> 3, h = bh & 7;
    float o = gnum[t] / gden[bh];
    attn[(size_t)b * SLEN * EMBED + h * HDIM + d] = f2bf(o);
}

// ---------------------------------------------------------------------------
// Kernel 4: windowed attention v4 — S^T MFMA, gll staging, dbuf LDS.
// grid (32 tiles, HEADS, BATCH), 256 thr (4 waves, wave w = rows w*16..+15).
// ---------------------------------------------------------------------------
__global__ __launch_bounds__(256) void windowed_attn_v4(
    const float* __restrict__ q, const float* __restrict__ k,
    const float* __restrict__ v, const int* __restrict__ mask,
    const short* __restrict__ Qbf, const short* __restrict__ Kbf,
    const short* __restrict__ Vbf,
    const float* __restrict__ vsum, const float* __restrict__ nvalid,
    short* __restrict__ attn) {
    int tile = blockIdx.x, h = blockIdx.y, b = blockIdx.z;
    int r0 = tile * 64;
    int t = threadIdx.x, w = t >> 6, l = t & 63;
    int lg = l >> 4, lr = l & 15;

    __shared__ __align__(16) short k_s[2][4096];
    __shared__ __align__(16) short v_s[2][4096];
    __shared__ __align__(16) short wT_s[4][16][72];  // per-wave, padded rows
    __shared__ float rsum[64];

    size_t hb = (size_t)(b * HEADS + h) * NCHUNK;

    // Q B-frags, direct global->reg (frag layout)
    const short* qtile = Qbf + (hb + tile) * 4096;
    bf16x8 qb0 = *(const bf16x8*)&qtile[lidx(w * 16 + lr, lg)];
    bf16x8 qb1 = *(const bf16x8*)&qtile[lidx(w * 16 + lr, 4 + lg)];

    int c0 = tile - 2; if (c0 < 0) c0 = 0;
    int c1 = tile + 2; if (c1 > NCHUNK - 1) c1 = NCHUNK - 1;

    stage_chunk(Kbf + (hb + c0) * 4096, Vbf + (hb + c0) * 4096,
                &k_s[0][0], &v_s[0][0], t);

    int center = r0 + w * 16 + lr - 1;   // this lane's output row center (QK role)
    int lo = center - HALFW, hi = center + HALFW;

    f32x4 pv[4];
    #pragma unroll
    for (int dt = 0; dt < 4; ++dt) pv[dt] = (f32x4){0.f, 0.f, 0.f, 0.f};
    float dacc = 0.f;
    int cur = 0;

    asm volatile("s_waitcnt vmcnt(0)" ::: "memory");
    __syncthreads();

    for (int c = c0; c <= c1; ++c) {
        if (c < c1)
            stage_chunk(Kbf + (hb + c + 1) * 4096, Vbf + (hb + c + 1) * 4096,
                        &k_s[cur ^ 1][0], &v_s[cur ^ 1][0], t);
        int jc = c * 64;

        // ---- QK^T (S^T): A = K rows, B = Q ----
        #pragma unroll
        for (int jt = 0; jt < 4; ++jt) {
            bf16x8 ka0 = *(const bf16x8*)&k_s[cur][lidx(jt * 16 + lr, lg)];
            bf16x8 ka1 = *(const bf16x8*)&k_s[cur][lidx(jt * 16 + lr, 4 + lg)];
            f32x4 sT = (f32x4){0.f, 0.f, 0.f, 0.f};
            sT = MFMA16(ka0, qb0, sT);
            sT = MFMA16(ka1, qb1, sT);
            int jbase = jc + jt * 16 + lg * 4;
            s16x4 wq;
            #pragma unroll
            for (int r = 0; r < 4; ++r) {
                int j = jbase + r;
                float wgt = (j >= lo && j <= hi) ? (__expf(sT[r] * INV_SCALE) - 1.f) : 0.f;
                dacc += wgt;
                wq[r] = f2bf(wgt);
            }
            *(s16x4*)&wT_s[w][lr][jt * 16 + lg * 4] = wq;
        }

        // ---- PV: A = w^T strip (wave-private), B = V^T frags ----
        bf16x8 wa0 = *(const bf16x8*)&wT_s[w][lr][lg * 8];
        bf16x8 wa1 = *(const bf16x8*)&wT_s[w][lr][32 + lg * 8];
        #pragma unroll
        for (int dt = 0; dt < 4; ++dt) {
            bf16x8 va0 = *(const bf16x8*)&v_s[cur][lidx(dt * 16 + lr, lg)];
            bf16x8 va1 = *(const bf16x8*)&v_s[cur][lidx(dt * 16 + lr, 4 + lg)];
            pv[dt] = MFMA16(wa0, va0, pv[dt]);
            pv[dt] = MFMA16(wa1, va1, pv[dt]);
        }

        asm volatile("s_waitcnt vmcnt(0)" ::: "memory");
        __syncthreads();
        cur ^= 1;
    }

    // ---- single-key fixup: row r0, key jx = r0-129 (outside aligned chunks) ----
    float wfix = 0.f;
    int jx = r0 - 129;
    if (w == 0 && jx >= 0) {
        float qv = q[((size_t)b * SLEN + r0) * EMBED + h * HDIM + l];
        float kv = k[((size_t)b * SLEN + jx) * EMBED + h * HDIM + l];
        float dd = qv * kv;
        #pragma unroll
        for (int off = 32; off > 0; off >>= 1) dd += __shfl_xor(dd, off, 64);
        if (mask[b * SLEN + jx] != 0) wfix = __expf(dd * INV_SCALE) - 1.f;
        if (lg == 0) {
            #pragma unroll
            for (int dt = 0; dt < 4; ++dt)
                pv[dt][0] += wfix * v[((size_t)b * SLEN + jx) * EMBED + h * HDIM + dt * 16 + lr];
        }
    }

    // ---- row-sum reduce (rows live on lr; combine the 4 lg groups) ----
    dacc += __shfl_xor(dacc, 16, 64);
    dacc += __shfl_xor(dacc, 32, 64);
    if (lg == 0) rsum[w * 16 + lr] = dacc + ((w == 0 && lr == 0) ? wfix : 0.f);
    __syncthreads();

    // ---- epilogue: lane holds O[m=lg*4+r][d=dt*16+lr] ----
    float nv = nvalid[b];
    float invden[4];
    #pragma unroll
    for (int r = 0; r < 4; ++r)
        invden[r] = 1.f / (nv + rsum[w * 16 + lg * 4 + r]);
    #pragma unroll
    for (int dt = 0; dt < 4; ++dt) {
        float vs = vsum[b * EMBED + h * HDIM + dt * 16 + lr];
        #pragma unroll
        for (int r = 0; r < 4; ++r) {
            int row = r0 + w * 16 + lg * 4 + r;
            if (row != 0) {
                float o = (pv[dt][r] + vs) * invden[r];
                attn[((size_t)b * SLEN + row) * EMBED + h * HDIM + dt * 16 + lr] = f2bf(o);
            }
        }
    }
}

// ---------------------------------------------------------------------------
// Kernel 5: FC GEMM, bf16 MFMA. M=4096 N=512 K=512. BM=BN=64, BK=64.
// ---------------------------------------------------------------------------
__global__ __launch_bounds__(256) void fc_gemm_v2(
    const short* __restrict__ A, const short* __restrict__ W,
    const float* __restrict__ bias, float* __restrict__ C) {
    __shared__ __align__(16) short a_s[4096];
    __shared__ __align__(16) short b_s[4096];
    int m0 = blockIdx.x * 64;
    int n0 = blockIdx.y * 64;
    int t = threadIdx.x;
    int w = t >> 6, l = t & 63;
    int lg = l >> 4, lr = l & 15;
    int wr = w >> 1, wc = w & 1;

    f32x4 c[2][2];
    #pragma unroll
    for (int mt = 0; mt < 2; ++mt)
        #pragma unroll
        for (int nt = 0; nt < 2; ++nt) c[mt][nt] = (f32x4){0.f, 0.f, 0.f, 0.f};

    for (int k0 = 0; k0 < 512; k0 += 64) {
        #pragma unroll
        for (int p = 0; p < 2; ++p) {
            int idx = p * 256 + t;
            int row = idx >> 3, sg = idx & 7;
            bf16x8 av = *(const bf16x8*)&A[(size_t)(m0 + row) * 512 + k0 + sg * 8];
            *(bf16x8*)&a_s[lidx(row, sg)] = av;
            bf16x8 bv = *(const bf16x8*)&W[(size_t)(n0 + row) * 512 + k0 + sg * 8];
            *(bf16x8*)&b_s[lidx(row, sg)] = bv;
        }
        __syncthreads();

        bf16x8 af[2][2], bf_[2][2];
        #pragma unroll
        for (int mt = 0; mt < 2; ++mt) {
            af[mt][0] = *(const bf16x8*)&a_s[lidx(wr * 32 + mt * 16 + lr, lg)];
            af[mt][1] = *(const bf16x8*)&a_s[lidx(wr * 32 + mt * 16 + lr, 4 + lg)];
        }
        #pragma unroll
        for (int nt = 0; nt < 2; ++nt) {
            bf_[nt][0] = *(const bf16x8*)&b_s[lidx(wc * 32 + nt * 16 + lr, lg)];
            bf_[nt][1] = *(const bf16x8*)&b_s[lidx(wc * 32 + nt * 16 + lr, 4 + lg)];
        }
        #pragma unroll
        for (int mt = 0; mt < 2; ++mt)
            #pragma unroll
            for (int nt = 0; nt < 2; ++nt) {
                c[mt][nt] = MFMA16(af[mt][0], bf_[nt][0], c[mt][nt]);
                c[mt][nt] = MFMA16(af[mt][1], bf_[nt][1], c[mt][nt]);
            }
        __syncthreads();
    }

    #pragma unroll
    for (int mt = 0; mt < 2; ++mt)
        #pragma unroll
        for (int nt = 0; nt < 2; ++nt) {
            int n = n0 + wc * 32 + nt * 16 + lr;
            float bb = bias[n];
            #pragma unroll
            for (int reg = 0; reg < 4; ++reg) {
                int m = m0 + wr * 32 + mt * 16 + lg * 4 + reg;
                C[(size_t)m * 512 + n] = c[mt][nt][reg] + bb;
            }
        }
}

// ---------------------------------------------------------------------------
extern "C" void kernel_launch(void* const* d_in, const int* in_sizes, int n_in,
                              void* d_out, int out_size, void* d_ws, size_t ws_size,
                              hipStream_t stream) {
    const float* values = (const float*)d_in[0];
    const float* keys   = (const float*)d_in[1];
    const float* query  = (const float*)d_in[2];
    const int*   mask   = (const int*)d_in[3];
    const float* fc_w   = (const float*)d_in[4];
    const float* fc_b   = (const float*)d_in[5];
    float* out = (float*)d_out;

    short* attn = (short*)d_ws;                                   // 4 MB
    short* wbf  = attn + (size_t)BATCH * SLEN * EMBED;            // 0.5 MB
    short* Qbf  = wbf + (size_t)EMBED * EMBED;                    // 4 MB
    short* Kbf  = Qbf + (size_t)BATCH * HEADS * NCHUNK * 4096;    // 4 MB
    short* Vbf  = Kbf + (size_t)BATCH * HEADS * NCHUNK * 4096;    // 4 MB
    float* vsum   = (float*)(Vbf + (size_t)BATCH * HEADS * NCHUNK * 4096);
    float* nvalid = vsum + BATCH * EMBED;
    float* gnum   = nvalid + BATCH;
    float* gden   = gnum + BATCH * HEADS * HDIM;

    hipMemsetAsync(vsum, 0,
                   (BATCH * EMBED + BATCH + BATCH * HEADS * HDIM + BATCH * HEADS) * sizeof(float),
                   stream);

    wcvt<<<dim3(256), 256, 0, stream>>>(fc_w, wbf);
    prepass<<<dim3(NCHUNK, HEADS, BATCH), 256, 0, stream>>>(
        query, keys, values, mask, Qbf, Kbf, Vbf, gnum, gden, vsum, nvalid);
    global_attn_final<<<dim3(1), 1024, 0, stream>>>(gnum, gden, attn);
    windowed_attn_v4<<<dim3(NCHUNK, HEADS, BATCH), 256, 0, stream>>>(
        query, keys, values, mask, Qbf, Kbf, Vbf, vsum, nvalid, attn);
    fc_gemm_v2<<<dim3(4096 / 64, 512 / 64), 256, 0, stream>>>(attn, wbf, fc_b, out);
}

// Round 6
// 46.465 us; speedup vs baseline: 13.8628x; 1.1205x over previous
//
#include <hip/hip_runtime.h>
#include <math.h>

#define EMBED 512
#define HEADS 8
#define HDIM 64
#define SLEN 2048
#define BATCH 2
#define HALFW 128
#define NCHUNK 32
#define INV_SCALE 0.044194173824159216f  // 1/sqrt(512)

typedef short bf16x8 __attribute__((ext_vector_type(8)));
typedef short s16x4  __attribute__((ext_vector_type(4)));
typedef float f32x4  __attribute__((ext_vector_type(4)));

#define MFMA16(a, b, c) __builtin_amdgcn_mfma_f32_16x16x32_bf16(a, b, c, 0, 0, 0)

__device__ __forceinline__ short f2bf(float x) {
    union { float f; unsigned u; } v; v.f = x;
    unsigned r = v.u + 0x7FFFu + ((v.u >> 16) & 1u);  // RNE
    return (short)(r >> 16);
}

// Blocked-frag layout for a 64x64 bf16 tile (global AND LDS), XOR-swizzled:
// 16B fragment (row, seg) at short index ((seg*64) + (row^seg)) * 8.
// Frag reads & staging writes bank-conflict-free (R2-R5: SQ_LDS_BANK_CONFLICT=0).
__device__ __forceinline__ int lidx(int row, int seg) {
    return (((seg << 6) + (row ^ seg)) << 3);
}

// async global->LDS, 16B per lane. dest: wave-uniform base, HW adds lane*16.
__device__ __forceinline__ void gll16(const short* g, short* l) {
    __builtin_amdgcn_global_load_lds(
        (const __attribute__((address_space(1))) unsigned int*)g,
        (__attribute__((address_space(3))) unsigned int*)l, 16, 0, 0);
}

// identity-copy two 8KB frag tiles (layout preserved: dest off == src off)
__device__ __forceinline__ void stage_chunk(const short* s0, const short* s1,
                                            short* d0, short* d1, int t) {
    int off = t * 8;              // shorts
    int wb  = (t >> 6) * 512;     // wave-uniform LDS base (shorts)
    gll16(s0 + off,        d0 + wb);
    gll16(s0 + 2048 + off, d0 + 2048 + wb);
    gll16(s1 + off,        d1 + wb);
    gll16(s1 + 2048 + off, d1 + 2048 + wb);
}

// ---------------------------------------------------------------------------
// Kernel 1: prepass. grid (NCHUNK+4, HEADS, BATCH), 256 thr.
//  c <  NCHUNK: Qbf/Kbf/Vbf bf16 frag conversion (K rows zeroed where mask==0,
//               V transposed to (d,j)); row-0 global-attn partials; vsum/nvalid.
//  c >= NCHUNK: fc_w -> Wbf frag-tile conversion (64 tiles over 64 blocks).
// ---------------------------------------------------------------------------
__global__ __launch_bounds__(256) void prepass(
    const float* __restrict__ q, const float* __restrict__ k,
    const float* __restrict__ v, const int* __restrict__ mask,
    const float* __restrict__ fcw,
    short* __restrict__ Qbf, short* __restrict__ Kbf, short* __restrict__ Vbf,
    short* __restrict__ Wbf,
    float* __restrict__ gnum, float* __restrict__ gden,
    float* __restrict__ vsum, float* __restrict__ nvalid) {
    int c = blockIdx.x, h = blockIdx.y, b = blockIdx.z;
    int t = threadIdx.x, w = t >> 6, l = t & 63;

    if (c >= NCHUNK) {            // ---- fc_w tile (nb, kt=h) -> Wbf frags ----
        int nb = b * 4 + (c - NCHUNK);
        size_t base = (size_t)(nb * 8 + h) * 4096;
        #pragma unroll
        for (int p = 0; p < 4; ++p) {
            int idx = p * 256 + t, row = idx >> 4, kg = idx & 15;
            float4 f = *(const float4*)(fcw + (size_t)(nb * 64 + row) * EMBED + h * 64 + kg * 4);
            s16x4 o;
            o[0] = f2bf(f.x); o[1] = f2bf(f.y); o[2] = f2bf(f.z); o[3] = f2bf(f.w);
            *(s16x4*)&Wbf[base + lidx(row, kg >> 1) + (kg & 1) * 4] = o;
        }
        return;
    }

    int j0 = c * 64;
    __shared__ float q0s[HDIM];
    __shared__ float wls[64];
    __shared__ int   m_s[64];
    __shared__ float vbuf[64][68];
    __shared__ float red[4][HDIM];
    __shared__ float redv[4][HDIM];

    if (t < 64) {
        q0s[t] = q[(size_t)b * SLEN * EMBED + h * HDIM + t];
        m_s[t] = mask[b * SLEN + j0 + t];
    }
    __syncthreads();

    size_t fragbase = ((size_t)(b * HEADS + h) * NCHUNK + c) * 4096;

    // ---- Q tile -> Qbf frags ----
    #pragma unroll
    for (int p = 0; p < 4; ++p) {
        int idx = p * 256 + t, row = idx >> 4, kg = idx & 15;
        float4 f = *(const float4*)(q + ((size_t)b * SLEN + j0 + row) * EMBED + h * HDIM + kg * 4);
        s16x4 o;
        o[0] = f2bf(f.x); o[1] = f2bf(f.y); o[2] = f2bf(f.z); o[3] = f2bf(f.w);
        *(s16x4*)&Qbf[fragbase + lidx(row, kg >> 1) + (kg & 1) * 4] = o;
    }

    // ---- K chunk -> Kbf frags (masked rows zeroed) + row-0 dot ----
    #pragma unroll
    for (int p = 0; p < 4; ++p) {
        int idx = p * 256 + t, row = idx >> 4, kg = idx & 15;
        float4 f = *(const float4*)(k + ((size_t)b * SLEN + j0 + row) * EMBED + h * HDIM + kg * 4);
        float dot = q0s[kg*4+0]*f.x + q0s[kg*4+1]*f.y + q0s[kg*4+2]*f.z + q0s[kg*4+3]*f.w;
        dot += __shfl_xor(dot, 1, 64);
        dot += __shfl_xor(dot, 2, 64);
        dot += __shfl_xor(dot, 4, 64);
        dot += __shfl_xor(dot, 8, 64);
        if ((t & 15) == 0) wls[row] = __expf(dot * INV_SCALE);
        if (!m_s[row]) f = make_float4(0.f, 0.f, 0.f, 0.f);
        s16x4 o;
        o[0] = f2bf(f.x); o[1] = f2bf(f.y); o[2] = f2bf(f.z); o[3] = f2bf(f.w);
        *(s16x4*)&Kbf[fragbase + lidx(row, kg >> 1) + (kg & 1) * 4] = o;
    }

    // ---- V chunk -> LDS (fp32, padded) ----
    #pragma unroll
    for (int p = 0; p < 4; ++p) {
        int idx = p * 256 + t, row = idx >> 4, kg = idx & 15;
        float4 f = *(const float4*)(v + ((size_t)b * SLEN + j0 + row) * EMBED + h * HDIM + kg * 4);
        *(float4*)&vbuf[row][kg * 4] = f;
    }
    __syncthreads();

    // ---- row-0 PV + vsum partials: lane = d, wave w covers 16 j ----
    float num = 0.f, vs = 0.f;
    #pragma unroll
    for (int jj = 0; jj < 16; ++jj) {
        int jl = w * 16 + jj;
        float vv = vbuf[jl][l];
        num += wls[jl] * vv;
        if (m_s[jl]) vs += vv;
    }
    red[w][l] = num;
    redv[w][l] = vs;

    // ---- V -> Vbf transposed frags: thread (w,l): d=l, jseg = w*2+s ----
    #pragma unroll
    for (int s = 0; s < 2; ++s) {
        int jseg = w * 2 + s;
        bf16x8 o;
        #pragma unroll
        for (int e = 0; e < 8; ++e) o[e] = f2bf(vbuf[jseg * 8 + e][l]);
        *(bf16x8*)&Vbf[fragbase + lidx(l, jseg)] = o;
    }
    __syncthreads();

    if (w == 0) {
        atomicAdd(&gnum[((size_t)b * HEADS + h) * HDIM + l],
                  red[0][l] + red[1][l] + red[2][l] + red[3][l]);
        atomicAdd(&vsum[b * EMBED + h * HDIM + l],
                  redv[0][l] + redv[1][l] + redv[2][l] + redv[3][l]);
    } else if (w == 1) {
        float s = wls[l];
        #pragma unroll
        for (int off = 32; off > 0; off >>= 1) s += __shfl_xor(s, off, 64);
        if (l == 0) atomicAdd(&gden[b * HEADS + h], s);
    } else if (w == 2 && h == 0) {
        float cc = m_s[l] ? 1.f : 0.f;
        #pragma unroll
        for (int off = 32; off > 0; off >>= 1) cc += __shfl_xor(cc, off, 64);
        if (l == 0) atomicAdd(&nvalid[b], cc);
    }
}

// ---------------------------------------------------------------------------
// Kernel 2: windowed attention v5 — S^T MFMA, gll staging, dbuf LDS.
// Writes output directly as fc-A frag tiles (Abf). tile==0 blocks also
// finalize row 0 from gnum/gden (prepass atomics final at kernel boundary).
// ---------------------------------------------------------------------------
__global__ __launch_bounds__(256) void windowed_attn_v5(
    const float* __restrict__ q, const float* __restrict__ k,
    const float* __restrict__ v, const int* __restrict__ mask,
    const short* __restrict__ Qbf, const short* __restrict__ Kbf,
    const short* __restrict__ Vbf,
    const float* __restrict__ vsum, const float* __restrict__ nvalid,
    const float* __restrict__ gnum, const float* __restrict__ gden,
    short* __restrict__ Abf) {
    int tile = blockIdx.x, h = blockIdx.y, b = blockIdx.z;
    int r0 = tile * 64;
    int t = threadIdx.x, w = t >> 6, l = t & 63;
    int lg = l >> 4, lr = l & 15;

    __shared__ __align__(16) short k_s[2][4096];
    __shared__ __align__(16) short v_s[2][4096];
    __shared__ __align__(16) short wT_s[4][16][72];
    __shared__ float rsum[64];

    size_t hb = (size_t)(b * HEADS + h) * NCHUNK;

    const short* qtile = Qbf + (hb + tile) * 4096;
    bf16x8 qb0 = *(const bf16x8*)&qtile[lidx(w * 16 + lr, lg)];
    bf16x8 qb1 = *(const bf16x8*)&qtile[lidx(w * 16 + lr, 4 + lg)];

    int c0 = tile - 2; if (c0 < 0) c0 = 0;
    int c1 = tile + 2; if (c1 > NCHUNK - 1) c1 = NCHUNK - 1;

    stage_chunk(Kbf + (hb + c0) * 4096, Vbf + (hb + c0) * 4096,
                &k_s[0][0], &v_s[0][0], t);

    int center = r0 + w * 16 + lr - 1;
    int lo = center - HALFW, hi = center + HALFW;

    f32x4 pv[4];
    #pragma unroll
    for (int dt = 0; dt < 4; ++dt) pv[dt] = (f32x4){0.f, 0.f, 0.f, 0.f};
    float dacc = 0.f;
    int cur = 0;

    asm volatile("s_waitcnt vmcnt(0)" ::: "memory");
    __syncthreads();

    for (int c = c0; c <= c1; ++c) {
        if (c < c1)
            stage_chunk(Kbf + (hb + c + 1) * 4096, Vbf + (hb + c + 1) * 4096,
                        &k_s[cur ^ 1][0], &v_s[cur ^ 1][0], t);
        int jc = c * 64;

        // ---- QK^T (S^T): A = K rows, B = Q ----
        #pragma unroll
        for (int jt = 0; jt < 4; ++jt) {
            bf16x8 ka0 = *(const bf16x8*)&k_s[cur][lidx(jt * 16 + lr, lg)];
            bf16x8 ka1 = *(const bf16x8*)&k_s[cur][lidx(jt * 16 + lr, 4 + lg)];
            f32x4 sT = (f32x4){0.f, 0.f, 0.f, 0.f};
            sT = MFMA16(ka0, qb0, sT);
            sT = MFMA16(ka1, qb1, sT);
            int jbase = jc + jt * 16 + lg * 4;
            s16x4 wq;
            #pragma unroll
            for (int r = 0; r < 4; ++r) {
                int j = jbase + r;
                float wgt = (j >= lo && j <= hi) ? (__expf(sT[r] * INV_SCALE) - 1.f) : 0.f;
                dacc += wgt;
                wq[r] = f2bf(wgt);
            }
            *(s16x4*)&wT_s[w][lr][jt * 16 + lg * 4] = wq;
        }

        // ---- PV: A = w^T strip (wave-private), B = V^T frags ----
        bf16x8 wa0 = *(const bf16x8*)&wT_s[w][lr][lg * 8];
        bf16x8 wa1 = *(const bf16x8*)&wT_s[w][lr][32 + lg * 8];
        #pragma unroll
        for (int dt = 0; dt < 4; ++dt) {
            bf16x8 va0 = *(const bf16x8*)&v_s[cur][lidx(dt * 16 + lr, lg)];
            bf16x8 va1 = *(const bf16x8*)&v_s[cur][lidx(dt * 16 + lr, 4 + lg)];
            pv[dt] = MFMA16(wa0, va0, pv[dt]);
            pv[dt] = MFMA16(wa1, va1, pv[dt]);
        }

        asm volatile("s_waitcnt vmcnt(0)" ::: "memory");
        __syncthreads();
        cur ^= 1;
    }

    // ---- single-key fixup: row r0, key jx = r0-129 ----
    float wfix = 0.f;
    int jx = r0 - 129;
    if (w == 0 && jx >= 0) {
        float qv = q[((size_t)b * SLEN + r0) * EMBED + h * HDIM + l];
        float kv = k[((size_t)b * SLEN + jx) * EMBED + h * HDIM + l];
        float dd = qv * kv;
        #pragma unroll
        for (int off = 32; off > 0; off >>= 1) dd += __shfl_xor(dd, off, 64);
        if (mask[b * SLEN + jx] != 0) wfix = __expf(dd * INV_SCALE) - 1.f;
        if (lg == 0) {
            #pragma unroll
            for (int dt = 0; dt < 4; ++dt)
                pv[dt][0] += wfix * v[((size_t)b * SLEN + jx) * EMBED + h * HDIM + dt * 16 + lr];
        }
    }

    // ---- row-sum reduce ----
    dacc += __shfl_xor(dacc, 16, 64);
    dacc += __shfl_xor(dacc, 32, 64);
    if (lg == 0) rsum[w * 16 + lr] = dacc + ((w == 0 && lr == 0) ? wfix : 0.f);
    __syncthreads();

    // ---- epilogue: write fc-A frag tile (row 0 from gnum/gden) ----
    float nv = nvalid[b];
    float invden[4];
    #pragma unroll
    for (int r = 0; r < 4; ++r)
        invden[r] = 1.f / (nv + rsum[w * 16 + lg * 4 + r]);

    short* Atile = Abf + ((size_t)(b * NCHUNK + tile) * 8 + h) * 4096;
    int bh = b * HEADS + h;
    #pragma unroll
    for (int dt = 0; dt < 4; ++dt) {
        int d = dt * 16 + lr;
        float vs = vsum[b * EMBED + h * HDIM + d];
        #pragma unroll
        for (int r = 0; r < 4; ++r) {
            int row_local = w * 16 + lg * 4 + r;
            float o;
            if (tile == 0 && row_local == 0)
                o = gnum[(size_t)bh * HDIM + d] / gden[bh];
            else
                o = (pv[dt][r] + vs) * invden[r];
            Atile[lidx(row_local, d >> 3) + (d & 7)] = f2bf(o);
        }
    }
}

// ---------------------------------------------------------------------------
// Kernel 3: FC GEMM v3 — frag-tile inputs, gll16 dbuf staging, 1 barrier/K-tile.
// C[m][n] = sum_k A[m][k]*W[n][k] + bias[n].  grid (64 m-tiles, 8 n-tiles).
// ---------------------------------------------------------------------------
__global__ __launch_bounds__(256) void fc_gemm_v3(
    const short* __restrict__ Abf, const short* __restrict__ Wbf,
    const float* __restrict__ bias, float* __restrict__ C) {
    int bm = blockIdx.x;          // 0..63
    int nb = blockIdx.y;          // 0..7
    int t = threadIdx.x, w = t >> 6, l = t & 63;
    int lg = l >> 4, lr = l & 15;
    int wr = w >> 1, wc = w & 1;

    __shared__ __align__(16) short a_s[2][4096];
    __shared__ __align__(16) short b_s[2][4096];

    f32x4 acc[2][2];
    #pragma unroll
    for (int mt = 0; mt < 2; ++mt)
        #pragma unroll
        for (int nt = 0; nt < 2; ++nt) acc[mt][nt] = (f32x4){0.f, 0.f, 0.f, 0.f};

    stage_chunk(Abf + (size_t)(bm * 8 + 0) * 4096, Wbf + (size_t)(nb * 8 + 0) * 4096,
                &a_s[0][0], &b_s[0][0], t);
    asm volatile("s_waitcnt vmcnt(0)" ::: "memory");
    __syncthreads();
    int cur = 0;

    for (int kt = 0; kt < 8; ++kt) {
        if (kt < 7)
            stage_chunk(Abf + (size_t)(bm * 8 + kt + 1) * 4096,
                        Wbf + (size_t)(nb * 8 + kt + 1) * 4096,
                        &a_s[cur ^ 1][0], &b_s[cur ^ 1][0], t);

        bf16x8 af[2][2], bf_[2][2];
        #pragma unroll
        for (int mt = 0; mt < 2; ++mt) {
            af[mt][0] = *(const bf16x8*)&a_s[cur][lidx(wr * 32 + mt * 16 + lr, lg)];
            af[mt][1] = *(const bf16x8*)&a_s[cur][lidx(wr * 32 + mt * 16 + lr, 4 + lg)];
        }
        #pragma unroll
        for (int nt = 0; nt < 2; ++nt) {
            bf_[nt][0] = *(const bf16x8*)&b_s[cur][lidx(wc * 32 + nt * 16 + lr, lg)];
            bf_[nt][1] = *(const bf16x8*)&b_s[cur][lidx(wc * 32 + nt * 16 + lr, 4 + lg)];
        }
        #pragma unroll
        for (int mt = 0; mt < 2; ++mt)
            #pragma unroll
            for (int nt = 0; nt < 2; ++nt) {
                acc[mt][nt] = MFMA16(af[mt][0], bf_[nt][0], acc[mt][nt]);
                acc[mt][nt] = MFMA16(af[mt][1], bf_[nt][1], acc[mt][nt]);
            }

        asm volatile("s_waitcnt vmcnt(0)" ::: "memory");
        __syncthreads();
        cur ^= 1;
    }

    #pragma unroll
    for (int mt = 0; mt < 2; ++mt)
        #pragma unroll
        for (int nt = 0; nt < 2; ++nt) {
            int n = nb * 64 + wc * 32 + nt * 16 + lr;
            float bb = bias[n];
            #pragma unroll
            for (int reg = 0; reg < 4; ++reg) {
                int m = bm * 64 + wr * 32 + mt * 16 + lg * 4 + reg;
                C[(size_t)m * 512 + n] = acc[mt][nt][reg] + bb;
            }
        }
}

// ---------------------------------------------------------------------------
extern "C" void kernel_launch(void* const* d_in, const int* in_sizes, int n_in,
                              void* d_out, int out_size, void* d_ws, size_t ws_size,
                              hipStream_t stream) {
    const float* values = (const float*)d_in[0];
    const float* keys   = (const float*)d_in[1];
    const float* query  = (const float*)d_in[2];
    const int*   mask   = (const int*)d_in[3];
    const float* fc_w   = (const float*)d_in[4];
    const float* fc_b   = (const float*)d_in[5];
    float* out = (float*)d_out;

    short* Abf = (short*)d_ws;                                    // 4 MB (frag tiles)
    short* Wbf = Abf + (size_t)BATCH * SLEN * EMBED;              // 512 KB
    short* Qbf = Wbf + (size_t)EMBED * EMBED;                     // 4 MB
    short* Kbf = Qbf + (size_t)BATCH * HEADS * NCHUNK * 4096;     // 4 MB
    short* Vbf = Kbf + (size_t)BATCH * HEADS * NCHUNK * 4096;     // 4 MB
    float* vsum   = (float*)(Vbf + (size_t)BATCH * HEADS * NCHUNK * 4096);
    float* nvalid = vsum + BATCH * EMBED;
    float* gnum   = nvalid + BATCH;
    float* gden   = gnum + BATCH * HEADS * HDIM;

    hipMemsetAsync(vsum, 0,
                   (BATCH * EMBED + BATCH + BATCH * HEADS * HDIM + BATCH * HEADS) * sizeof(float),
                   stream);

    prepass<<<dim3(NCHUNK + 4, HEADS, BATCH), 256, 0, stream>>>(
        query, keys, values, mask, fc_w, Qbf, Kbf, Vbf, Wbf, gnum, gden, vsum, nvalid);
    windowed_attn_v5<<<dim3(NCHUNK, HEADS, BATCH), 256, 0, stream>>>(
        query, keys, values, mask, Qbf, Kbf, Vbf, vsum, nvalid, gnum, gden, Abf);
    fc_gemm_v3<<<dim3(BATCH * NCHUNK, EMBED / 64), 256, 0, stream>>>(
        Abf, Wbf, fc_b, out);
}